// Round 2
// baseline (4868.776 us; speedup 1.0000x reference)
//
#include <hip/hip_runtime.h>

#define NR 32768   // rows (b*w*h)
#define CD 256     // emb dim
#define KD 8192    // dict size

// ---- workspace float offsets ----
#define WS_FLATT   0ull          // 256 x 32768
#define WS_EMBEDT  8388608ull    // 256 x 8192
#define WS_E2      10485760ull   // 8192 (fast e2, main path)
#define WS_IDS     10493952ull   // 32768 ints
#define WS_LOSS    10526720ull   // 1 float
#define WS_FLAGCNT 10526721ull   // 1 int
#define WS_FLAGLST 10526722ull   // up to 32768 ints
#define WS_E2NP    10559490ull   // 8192 (numpy-pairwise-emulated e2)

// ---- output float offsets (concatenated tuple) ----
#define OUT_ST   0ull            // 32*256*32*32
#define OUT_LOSS 8388608ull      // 1
#define OUT_IDS  8388609ull      // 32*32*32
#define OUT_NEMB 8421377ull      // 8192*256
#define OUT_NUM  10518529ull     // 8192
#define OUT_ENC  10526721ull     // 8192*256

// numpy pairwise_sum for a 128-block: 8 accumulators, fixed combine tree.
__device__ __forceinline__ float np_pw128(const float* p) {
    float r0 = p[0], r1 = p[1], r2 = p[2], r3 = p[3];
    float r4 = p[4], r5 = p[5], r6 = p[6], r7 = p[7];
    for (int i = 8; i < 128; i += 8) {
        r0 += p[i + 0]; r1 += p[i + 1]; r2 += p[i + 2]; r3 += p[i + 3];
        r4 += p[i + 4]; r5 += p[i + 5]; r6 += p[i + 6]; r7 += p[i + 7];
    }
    return ((r0 + r1) + (r2 + r3)) + ((r4 + r5) + (r6 + r7));
}

// x (b,c,h,w) -> flatT[c][n], n = b*1024 + w*32 + h
__global__ void k_xpose(const float* __restrict__ x, float* __restrict__ flatT) {
    int b = blockIdx.x >> 8, c = blockIdx.x & 255;
    __shared__ float t[32][33];
    const float* src = x + ((size_t)(b * 256 + c)) * 1024;  // [h][w]
    int tid = threadIdx.x;
    #pragma unroll
    for (int i = 0; i < 4; ++i) { int e = tid + i * 256; t[e >> 5][e & 31] = src[e]; }
    __syncthreads();
    float* dst = flatT + (size_t)c * NR + b * 1024;         // [w][h]
    #pragma unroll
    for (int i = 0; i < 4; ++i) { int e = tid + i * 256; dst[e] = t[e & 31][e >> 5]; }
}

// embed (k,c) -> embedT[c][k]
__global__ void k_epose(const float* __restrict__ embed, float* __restrict__ embedT) {
    int kt = blockIdx.x >> 2, ct = blockIdx.x & 3;
    __shared__ float t[64][65];
    int tid = threadIdx.x;
    #pragma unroll
    for (int i = 0; i < 16; ++i) {
        int e = tid + i * 256; int r = e >> 6, c = e & 63;
        t[r][c] = embed[(size_t)(kt * 64 + r) * CD + ct * 64 + c];
    }
    __syncthreads();
    #pragma unroll
    for (int i = 0; i < 16; ++i) {
        int e = tid + i * 256; int c = e >> 6, r = e & 63;
        embedT[(size_t)(ct * 64 + c) * KD + kt * 64 + r] = t[r][c];
    }
}

// fast e2 (main path only; error ~1e-7 << 2e-3 flag margin)
__global__ void k_e2(const float* __restrict__ embed, float* __restrict__ e2) {
    int wave = threadIdx.x >> 6, lane = threadIdx.x & 63;
    int k = blockIdx.x * 4 + wave;
    float4 v = *(const float4*)(embed + (size_t)k * CD + lane * 4);
    float s = v.x * v.x + v.y * v.y + v.z * v.z + v.w * v.w;
    #pragma unroll
    for (int off = 1; off < 64; off <<= 1) s += __shfl_xor(s, off);
    if (lane == 0) e2[k] = s;
}

// numpy-emulated e2: products rounded to fp32 in LDS, pairwise-summed.
__global__ void k_e2np(const float* __restrict__ embed, float* __restrict__ e2np) {
    __shared__ float sq[256];
    const int tid = threadIdx.x;
    for (int kk = 0; kk < 32; ++kk) {
        const int k = blockIdx.x * 32 + kk;
        const float v = embed[(size_t)k * CD + tid];
        sq[tid] = v * v;          // product rounds to fp32 at LDS store
        __syncthreads();
        if (tid == 0) e2np[k] = np_pw128(sq) + np_pw128(sq + 128);
        __syncthreads();
    }
}

// block: 64 rows x all 8192 codes; maximize m = dot - 0.5*e2  (== argmin d2)
__global__ __launch_bounds__(256) void k_argmin(
    const float* __restrict__ flatT, const float* __restrict__ embedT,
    const float* __restrict__ e2, int* __restrict__ ids,
    int* __restrict__ flag_cnt, int* __restrict__ flag_list)
{
    __shared__ float a_lds[CD][64];   // 64 KB  a_lds[c][r]
    __shared__ float b_lds[64][64];   // 16 KB  b_lds[cc][k]
    const int tid = threadIdx.x;
    const int n0 = blockIdx.x * 64;
    for (int i = 0; i < 64; ++i) {
        int e = i * 256 + tid;
        a_lds[e >> 6][e & 63] = flatT[(size_t)(e >> 6) * NR + n0 + (e & 63)];
    }
    const int ty = tid >> 4, tx = tid & 15;
    const int r0 = ty * 4;
    float m1[4], m2[4]; int i1[4];
    #pragma unroll
    for (int a = 0; a < 4; ++a) { m1[a] = -3.4e38f; m2[a] = -3.4e38f; i1[a] = 0; }

    for (int kt = 0; kt < KD / 64; ++kt) {
        const int k0 = kt * 64;
        const float4 ev = *(const float4*)(e2 + k0 + tx * 4);
        float acc[4][4];
        #pragma unroll
        for (int a = 0; a < 4; ++a) {
            acc[a][0] = -0.5f * ev.x; acc[a][1] = -0.5f * ev.y;
            acc[a][2] = -0.5f * ev.z; acc[a][3] = -0.5f * ev.w;
        }
        for (int ch = 0; ch < 4; ++ch) {
            __syncthreads();
            #pragma unroll
            for (int i = 0; i < 16; ++i) {
                int e = i * 256 + tid;
                b_lds[e >> 6][e & 63] =
                    embedT[(size_t)(ch * 64 + (e >> 6)) * KD + k0 + (e & 63)];
            }
            __syncthreads();
            #pragma unroll 16
            for (int cc = 0; cc < 64; ++cc) {
                const float4 av = *(const float4*)&a_lds[ch * 64 + cc][r0];
                const float4 bv = *(const float4*)&b_lds[cc][tx * 4];
                acc[0][0] = fmaf(av.x, bv.x, acc[0][0]);
                acc[0][1] = fmaf(av.x, bv.y, acc[0][1]);
                acc[0][2] = fmaf(av.x, bv.z, acc[0][2]);
                acc[0][3] = fmaf(av.x, bv.w, acc[0][3]);
                acc[1][0] = fmaf(av.y, bv.x, acc[1][0]);
                acc[1][1] = fmaf(av.y, bv.y, acc[1][1]);
                acc[1][2] = fmaf(av.y, bv.z, acc[1][2]);
                acc[1][3] = fmaf(av.y, bv.w, acc[1][3]);
                acc[2][0] = fmaf(av.z, bv.x, acc[2][0]);
                acc[2][1] = fmaf(av.z, bv.y, acc[2][1]);
                acc[2][2] = fmaf(av.z, bv.z, acc[2][2]);
                acc[2][3] = fmaf(av.z, bv.w, acc[2][3]);
                acc[3][0] = fmaf(av.w, bv.x, acc[3][0]);
                acc[3][1] = fmaf(av.w, bv.y, acc[3][1]);
                acc[3][2] = fmaf(av.w, bv.z, acc[3][2]);
                acc[3][3] = fmaf(av.w, bv.w, acc[3][3]);
            }
        }
        #pragma unroll
        for (int a = 0; a < 4; ++a) {
            #pragma unroll
            for (int b = 0; b < 4; ++b) {
                float v = acc[a][b];
                int kk = k0 + tx * 4 + b;
                if (v > m1[a])      { m2[a] = m1[a]; m1[a] = v; i1[a] = kk; }
                else if (v > m2[a]) { m2[a] = v; }
            }
        }
    }
    // merge top-2 across the 16 tx lanes of each row group
    #pragma unroll
    for (int off = 1; off < 16; off <<= 1) {
        #pragma unroll
        for (int a = 0; a < 4; ++a) {
            float om1 = __shfl_xor(m1[a], off);
            float om2 = __shfl_xor(m2[a], off);
            int   oi1 = __shfl_xor(i1[a], off);
            if (om1 > m1[a] || (om1 == m1[a] && oi1 < i1[a])) {
                m2[a] = fmaxf(m1[a], om2); m1[a] = om1; i1[a] = oi1;
            } else {
                m2[a] = fmaxf(m2[a], om1);
            }
        }
    }
    if (tx == 0) {
        #pragma unroll
        for (int a = 0; a < 4; ++a) {
            int n = n0 + r0 + a;
            ids[n] = i1[a];
            if (m1[a] - m2[a] < 2e-3f) {
                int p = atomicAdd(flag_cnt, 1);
                flag_list[p] = n;
            }
        }
    }
}

// numpy-fp32-path emulation for near-tie rows:
// d2[k] = fl(fl(x2_np - 2*dot_np[k]) + e2_np[k]); argmin, ties -> lowest k.
// dot_np = sequential fp32 fma chain over c (BLAS microkernel order).
__global__ __launch_bounds__(256) void k_rescore(
    const float* __restrict__ flatT, const float* __restrict__ embedT,
    const float* __restrict__ e2np, const int* __restrict__ flag_cnt,
    const int* __restrict__ flag_list, int* __restrict__ ids)
{
    __shared__ float row[256];
    __shared__ float sq[256];
    __shared__ float bdA[256];
    __shared__ int   biA[256];
    const int tid = threadIdx.x;
    const int cnt = *flag_cnt;
    for (int f = blockIdx.x; f < cnt; f += gridDim.x) {
        const int n = flag_list[f];
        const float v = flatT[(size_t)tid * NR + n];
        row[tid] = v;
        sq[tid] = v * v;              // product rounds to fp32 at LDS store
        __syncthreads();
        const float x2 = np_pw128(sq) + np_pw128(sq + 128);

        float acc[32];
        #pragma unroll
        for (int j = 0; j < 32; ++j) acc[j] = 0.0f;
        // 32 k-chains per thread, each chain sequential in c (exact BLAS order)
        for (int c = 0; c < 256; ++c) {
            const float av = row[c];
            const float* bp = embedT + (size_t)c * KD + tid * 4;
            #pragma unroll
            for (int j2 = 0; j2 < 8; ++j2) {
                const float4 bv = *(const float4*)(bp + j2 * 1024);
                acc[j2 * 4 + 0] = fmaf(av, bv.x, acc[j2 * 4 + 0]);
                acc[j2 * 4 + 1] = fmaf(av, bv.y, acc[j2 * 4 + 1]);
                acc[j2 * 4 + 2] = fmaf(av, bv.z, acc[j2 * 4 + 2]);
                acc[j2 * 4 + 3] = fmaf(av, bv.w, acc[j2 * 4 + 3]);
            }
        }
        float bd = 3.4e38f; int bi = 0x7fffffff;
        #pragma unroll
        for (int j2 = 0; j2 < 8; ++j2) {
            #pragma unroll
            for (int e = 0; e < 4; ++e) {
                const int k = j2 * 1024 + tid * 4 + e;
                // fl(2*acc) is exact; fl(x2 - 2acc) then fl(+ e2) matches np op order
                const float d2 = (x2 - 2.0f * acc[j2 * 4 + e]) + e2np[k];
                if (d2 < bd || (d2 == bd && k < bi)) { bd = d2; bi = k; }
            }
        }
        bdA[tid] = bd; biA[tid] = bi;
        __syncthreads();
        if (tid == 0) {
            float b = bdA[0]; int j1 = biA[0];
            for (int i = 1; i < 256; ++i) {
                if (bdA[i] < b || (bdA[i] == b && biA[i] < j1)) { b = bdA[i]; j1 = biA[i]; }
            }
            ids[n] = j1;
        }
        __syncthreads();
    }
}

// st_out (= vqs) + loss partial sums
__global__ void k_output(const float* __restrict__ x, const float* __restrict__ embed,
                         const int* __restrict__ ids, float* __restrict__ st,
                         float* __restrict__ loss_ws)
{
    const size_t base = ((size_t)blockIdx.x * 256 + threadIdx.x) * 4;
    const int w = (int)(base & 31);
    const int h = (int)((base >> 5) & 31);
    const int c = (int)((base >> 10) & 255);
    const int b = (int)(base >> 18);
    const float4 xv = *(const float4*)(x + base);
    const int nb = b * 1024 + h;
    const float vq0 = embed[(size_t)ids[nb + (w + 0) * 32] * CD + c];
    const float vq1 = embed[(size_t)ids[nb + (w + 1) * 32] * CD + c];
    const float vq2 = embed[(size_t)ids[nb + (w + 2) * 32] * CD + c];
    const float vq3 = embed[(size_t)ids[nb + (w + 3) * 32] * CD + c];
    *(float4*)(st + base) = make_float4(vq0, vq1, vq2, vq3);
    const float d0 = vq0 - xv.x, d1 = vq1 - xv.y, d2 = vq2 - xv.z, d3 = vq3 - xv.w;
    float s = d0 * d0 + d1 * d1 + d2 * d2 + d3 * d3;
    #pragma unroll
    for (int off = 1; off < 64; off <<= 1) s += __shfl_xor(s, off);
    if ((threadIdx.x & 63) == 0) atomicAdd(loss_ws, s);
}

__global__ void k_ids(const int* __restrict__ ids, float* __restrict__ ids_out) {
    int e = blockIdx.x * 256 + threadIdx.x;
    int b = e >> 10, h = (e >> 5) & 31, w = e & 31;
    ids_out[e] = (float)ids[b * 1024 + w * 32 + h];
}

__global__ void k_count(const int* __restrict__ ids, float* __restrict__ track_num) {
    int n = blockIdx.x * 256 + threadIdx.x;
    atomicAdd(&track_num[ids[n]], 1.0f);
}

__global__ void k_scatter(const float* __restrict__ flatT, const int* __restrict__ ids,
                          float* __restrict__ track_enc)
{
    const int nb = blockIdx.x & 127, cg = blockIdx.x >> 7;
    const int n = nb * 256 + threadIdx.x;
    const int id = ids[n];
    float* dst = track_enc + (size_t)id * CD;
    #pragma unroll
    for (int j = 0; j < 4; ++j) {
        int c = cg * 4 + j;
        atomicAdd(&dst[c], flatT[(size_t)c * NR + n]);
    }
}

__global__ void k_final(const float* __restrict__ track_num, const float* __restrict__ track_enc,
                        float* __restrict__ new_embed, const float* __restrict__ loss_ws,
                        float* __restrict__ loss_out)
{
    const size_t e = (size_t)blockIdx.x * 256 + threadIdx.x;
    const int k = (int)(e >> 8);
    const float factor = 1.0f + (1e-5f * 8192.0f) / 32768.0f;  // sum(counts) == 32768 exactly
    new_embed[e] = track_enc[e] * factor / (track_num[k] + 1e-5f);
    if (e == 0) loss_out[0] = loss_ws[0] * (1.0f / 8388608.0f);
}

extern "C" void kernel_launch(void* const* d_in, const int* in_sizes, int n_in,
                              void* d_out, int out_size, void* d_ws, size_t ws_size,
                              hipStream_t stream)
{
    const float* x     = (const float*)d_in[0];
    const float* embed = (const float*)d_in[1];
    float* out = (float*)d_out;
    float* ws  = (float*)d_ws;

    float* flatT     = ws + WS_FLATT;
    float* embedT    = ws + WS_EMBEDT;
    float* e2        = ws + WS_E2;
    int*   ids       = (int*)(ws + WS_IDS);
    float* loss_ws   = ws + WS_LOSS;
    int*   flag_cnt  = (int*)(ws + WS_FLAGCNT);
    int*   flag_list = (int*)(ws + WS_FLAGLST);
    float* e2np      = ws + WS_E2NP;

    // zero accumulators (track_num + track_enc are contiguous in out; loss+flag_cnt in ws)
    hipMemsetAsync(out + OUT_NUM, 0, (size_t)(KD + KD * CD) * sizeof(float), stream);
    hipMemsetAsync(ws + WS_LOSS, 0, 2 * sizeof(float), stream);

    k_xpose  <<<8192, 256, 0, stream>>>(x, flatT);
    k_epose  <<<512,  256, 0, stream>>>(embed, embedT);
    k_e2     <<<2048, 256, 0, stream>>>(embed, e2);
    k_e2np   <<<256,  256, 0, stream>>>(embed, e2np);
    k_argmin <<<512,  256, 0, stream>>>(flatT, embedT, e2, ids, flag_cnt, flag_list);
    k_rescore<<<128,  256, 0, stream>>>(flatT, embedT, e2np, flag_cnt, flag_list, ids);
    k_output <<<8192, 256, 0, stream>>>(x, embed, ids, out + OUT_ST, loss_ws);
    k_ids    <<<128,  256, 0, stream>>>(ids, out + OUT_IDS);
    k_count  <<<128,  256, 0, stream>>>(ids, out + OUT_NUM);
    k_scatter<<<8192, 256, 0, stream>>>(flatT, ids, out + OUT_ENC);
    k_final  <<<8192, 256, 0, stream>>>(out + OUT_NUM, out + OUT_ENC, out + OUT_NEMB,
                                        loss_ws, out + OUT_LOSS);
}

// Round 3
// 1731.522 us; speedup vs baseline: 2.8118x; 2.8118x over previous
//
#include <hip/hip_runtime.h>

#define NR 32768   // rows (b*w*h)
#define CD 256     // emb dim
#define KD 8192    // dict size

typedef __attribute__((ext_vector_type(8))) __bf16 bf16x8;
typedef __attribute__((ext_vector_type(4))) __bf16 bf16x4;
typedef __attribute__((ext_vector_type(4))) float f32x4;

// ---- workspace float offsets ----
#define F_AH      0ull          // bf16[32768][256] hi  (16MB)
#define F_AL      4194304ull    // bf16[32768][256] lo  (16MB)
#define F_BH      8388608ull    // bf16[8192][256] hi   (4MB)
#define F_BL      9437184ull    // bf16[8192][256] lo   (4MB)
#define F_EMBT    10485760ull   // fp32 embedT[256][8192] (8MB, rescore)
#define F_PM1     12582912ull   // f32 [32][32768]
#define F_PM2     13631488ull
#define F_PI1     14680064ull
#define F_E2      15728640ull   // 8192
#define F_E2NP    15736832ull   // 8192
#define F_IDS     15745024ull   // 32768 ints
#define F_FLAGCNT 15777792ull
#define F_LOSS    15777793ull
#define F_FLAGLST 15777794ull   // 32768 ints
#define F_COUNTS  15810562ull   // 8192 ints
#define F_CURSOR  15818754ull   // 8192 ints
#define F_OFFS    15826946ull   // 8192 ints
#define F_BUCKET  15835138ull   // 32768 ints

// ---- output float offsets ----
#define OUT_ST   0ull
#define OUT_LOSS 8388608ull
#define OUT_IDS  8388609ull
#define OUT_NEMB 8421377ull
#define OUT_NUM  10518529ull
#define OUT_ENC  10526721ull

// numpy pairwise_sum for a 128-block: 8 accumulators, fixed combine tree.
__device__ __forceinline__ float np_pw128(const float* p) {
    float r0 = p[0], r1 = p[1], r2 = p[2], r3 = p[3];
    float r4 = p[4], r5 = p[5], r6 = p[6], r7 = p[7];
    for (int i = 8; i < 128; i += 8) {
        r0 += p[i + 0]; r1 += p[i + 1]; r2 += p[i + 2]; r3 += p[i + 3];
        r4 += p[i + 4]; r5 += p[i + 5]; r6 += p[i + 6]; r7 += p[i + 7];
    }
    return ((r0 + r1) + (r2 + r3)) + ((r4 + r5) + (r6 + r7));
}

// x (b,c,h,w) -> a_hi/a_lo[n][c] bf16, n = b*1024 + w*32 + h
__global__ void k_cvt_x(const float* __restrict__ x,
                        __bf16* __restrict__ aH, __bf16* __restrict__ aL) {
    __shared__ float t[32 * 529];   // [c32][h16*33 + w]
    const int bx = blockIdx.x;
    const int b = bx >> 4, cg = (bx >> 1) & 7, h0 = (bx & 1) * 16;
    const int tid = threadIdx.x;
    const float* src = x + ((size_t)(b * 256 + cg * 32)) * 1024 + h0 * 32;
    for (int i = 0; i < 64; ++i) {
        int e = i * 256 + tid;
        int c = e >> 9, rem = e & 511;
        int hh = rem >> 5, w = rem & 31;
        t[c * 529 + hh * 33 + w] = src[(size_t)c * 1024 + hh * 32 + w];
    }
    __syncthreads();
    const int ni = tid >> 5, c = tid & 31;
    for (int i = 0; i < 64; ++i) {
        int ns = i * 8 + ni;             // 0..511 = w*16 + hh
        int w = ns >> 4, hh = ns & 15;
        float v = t[c * 529 + hh * 33 + w];
        __bf16 hi = (__bf16)v;
        __bf16 lo = (__bf16)(v - (float)hi);
        size_t o = ((size_t)(b * 1024 + w * 32 + h0 + hh)) * 256 + cg * 32 + c;
        aH[o] = hi; aL[o] = lo;
    }
}

// embed -> b_hi/b_lo bf16 (same layout, elementwise)
__global__ void k_cvt_e(const float* __restrict__ embed,
                        __bf16* __restrict__ bH, __bf16* __restrict__ bL) {
    size_t i = ((size_t)blockIdx.x * 256 + threadIdx.x) * 4;
    float4 v = *(const float4*)(embed + i);
    bf16x4 h, l;
    h[0] = (__bf16)v.x; l[0] = (__bf16)(v.x - (float)h[0]);
    h[1] = (__bf16)v.y; l[1] = (__bf16)(v.y - (float)h[1]);
    h[2] = (__bf16)v.z; l[2] = (__bf16)(v.z - (float)h[2]);
    h[3] = (__bf16)v.w; l[3] = (__bf16)(v.w - (float)h[3]);
    *(bf16x4*)&bH[i] = h;
    *(bf16x4*)&bL[i] = l;
}

// embed (k,c) -> embedT[c][k] fp32 (rescore only)
__global__ void k_epose(const float* __restrict__ embed, float* __restrict__ embedT) {
    int kt = blockIdx.x >> 2, ct = blockIdx.x & 3;
    __shared__ float t[64][65];
    int tid = threadIdx.x;
    #pragma unroll
    for (int i = 0; i < 16; ++i) {
        int e = tid + i * 256; int r = e >> 6, c = e & 63;
        t[r][c] = embed[(size_t)(kt * 64 + r) * CD + ct * 64 + c];
    }
    __syncthreads();
    #pragma unroll
    for (int i = 0; i < 16; ++i) {
        int e = tid + i * 256; int c = e >> 6, r = e & 63;
        embedT[(size_t)(ct * 64 + c) * KD + kt * 64 + r] = t[r][c];
    }
}

// fast e2 (main path)
__global__ void k_e2(const float* __restrict__ embed, float* __restrict__ e2) {
    int wave = threadIdx.x >> 6, lane = threadIdx.x & 63;
    int k = blockIdx.x * 4 + wave;
    float4 v = *(const float4*)(embed + (size_t)k * CD + lane * 4);
    float s = v.x * v.x + v.y * v.y + v.z * v.z + v.w * v.w;
    #pragma unroll
    for (int off = 1; off < 64; off <<= 1) s += __shfl_xor(s, off);
    if (lane == 0) e2[k] = s;
}

// numpy-emulated e2, wave-parallel: 8 lanes per k, exact pairwise tree.
__global__ void k_e2np(const float* __restrict__ embed, float* __restrict__ e2np) {
    const int lane = threadIdx.x & 63;
    const int wv = threadIdx.x >> 6;
    const int k = blockIdx.x * 32 + wv * 8 + (lane >> 3);
    const int j = lane & 7;
    float hsum[2];
    #pragma unroll
    for (int half = 0; half < 2; ++half) {
        float r = 0.f;
        for (int i = 0; i < 16; ++i) {
            float v = embed[(size_t)k * CD + half * 128 + j + i * 8];
            float sq = v * v;
            asm volatile("" : "+v"(sq));   // block fma-contraction: round v*v to fp32
            r += sq;
        }
        float s = r + __shfl_xor(r, 1);    // (r0+r1) etc (commutative = exact)
        s = s + __shfl_xor(s, 2);          // (r0+r1)+(r2+r3)
        s = s + __shfl_xor(s, 4);          // full 8-acc tree
        hsum[half] = s;
    }
    if (j == 0) e2np[k] = hsum[0] + hsum[1];
}

// MFMA argmin: 3-pass split-bf16 GEMM, tile 128 rows x 256 codes, BK=32, dbuf.
__global__ __launch_bounds__(512, 2) void k_mfma(
    const __bf16* __restrict__ aH, const __bf16* __restrict__ aL,
    const __bf16* __restrict__ bH, const __bf16* __restrict__ bL,
    const float* __restrict__ e2,
    float* __restrict__ pm1, float* __restrict__ pm2, int* __restrict__ pi1)
{
    __shared__ __bf16 lds[2][24576];    // per buf: aH[128][32], aL, bH[256][32], bL
    __shared__ float sm1[4][128], sm2[4][128];
    __shared__ int   si1[4][128];
    const int tid = threadIdx.x;
    const int w = tid >> 6, l = tid & 63;
    const int d = blockIdx.x;
    const int ct = (d & 7) * 4 + ((d >> 3) & 3);  // XCD-local B-slice (1MB -> L2)
    const int rt = d >> 5;
    const int n0 = rt * 128, k0 = ct * 256;
    const int wr = w >> 2, wc = w & 3;

    f32x4 acc[4][4];
    #pragma unroll
    for (int m = 0; m < 4; ++m)
        #pragma unroll
        for (int n = 0; n < 4; ++n)
            acc[m][n] = (f32x4){0.f, 0.f, 0.f, 0.f};

    const int lrow16 = l >> 2;
    const int lcol8  = (l & 3) << 3;

    auto STAGE = [&](int buf, int t) {
        const int c0 = t * 32;
        #pragma unroll
        for (int jj = 0; jj < 6; ++jj) {
            const int j = w * 6 + jj;
            const __bf16* gsrc; unsigned loff; int grow;
            if (j < 8)       { gsrc = aH; loff = (unsigned)j * 512;          grow = n0 + j * 16; }
            else if (j < 16) { gsrc = aL; loff = 4096 + (unsigned)(j - 8) * 512;  grow = n0 + (j - 8) * 16; }
            else if (j < 32) { gsrc = bH; loff = 8192 + (unsigned)(j - 16) * 512; grow = k0 + (j - 16) * 16; }
            else             { gsrc = bL; loff = 16384 + (unsigned)(j - 32) * 512; grow = k0 + (j - 32) * 16; }
            const __bf16* gp = gsrc + ((size_t)(grow + lrow16) * 256 + c0 + lcol8);
            __builtin_amdgcn_global_load_lds(
                (const __attribute__((address_space(1))) unsigned int*)gp,
                (__attribute__((address_space(3))) unsigned int*)&lds[buf][loff],
                16, 0, 0);
        }
    };

    auto COMPUTE = [&](int buf) {
        bf16x8 fa[4], fal[4], fb[4], fbl[4];
        const int lr = l & 15, ls = (l >> 4) << 3;
        #pragma unroll
        for (int m = 0; m < 4; ++m) {
            int r = wr * 64 + m * 16 + lr;
            fa[m]  = *(const bf16x8*)&lds[buf][r * 32 + ls];
            fal[m] = *(const bf16x8*)&lds[buf][4096 + r * 32 + ls];
        }
        #pragma unroll
        for (int n = 0; n < 4; ++n) {
            int kk = wc * 64 + n * 16 + lr;
            fb[n]  = *(const bf16x8*)&lds[buf][8192 + kk * 32 + ls];
            fbl[n] = *(const bf16x8*)&lds[buf][16384 + kk * 32 + ls];
        }
        #pragma unroll
        for (int m = 0; m < 4; ++m)
            #pragma unroll
            for (int n = 0; n < 4; ++n) {
                acc[m][n] = __builtin_amdgcn_mfma_f32_16x16x32_bf16(fa[m],  fb[n],  acc[m][n], 0, 0, 0);
                acc[m][n] = __builtin_amdgcn_mfma_f32_16x16x32_bf16(fa[m],  fbl[n], acc[m][n], 0, 0, 0);
                acc[m][n] = __builtin_amdgcn_mfma_f32_16x16x32_bf16(fal[m], fb[n],  acc[m][n], 0, 0, 0);
            }
    };

    STAGE(0, 0);
    __syncthreads();
    int cur = 0;
    for (int t = 0; t < 8; ++t) {
        if (t < 7) STAGE(cur ^ 1, t + 1);
        COMPUTE(cur);
        __syncthreads();
        cur ^= 1;
    }

    // epilogue: score = acc - 0.5*e2; per-row top-2 within this 256-col tile
    float e2v[4];
    #pragma unroll
    for (int n = 0; n < 4; ++n) e2v[n] = e2[k0 + wc * 64 + n * 16 + (l & 15)];
    float rm1[4][4], rm2[4][4]; int ri1[4][4];
    #pragma unroll
    for (int m = 0; m < 4; ++m)
        #pragma unroll
        for (int r = 0; r < 4; ++r) {
            float m1 = -3.4e38f, m2 = -3.4e38f; int i1 = 0;
            #pragma unroll
            for (int n = 0; n < 4; ++n) {
                float v = acc[m][n][r] - 0.5f * e2v[n];
                int kk = k0 + wc * 64 + n * 16 + (l & 15);
                if (v > m1)      { m2 = m1; m1 = v; i1 = kk; }
                else if (v > m2) { m2 = v; }
            }
            rm1[m][r] = m1; rm2[m][r] = m2; ri1[m][r] = i1;
        }
    #pragma unroll
    for (int off = 1; off < 16; off <<= 1) {
        #pragma unroll
        for (int m = 0; m < 4; ++m)
            #pragma unroll
            for (int r = 0; r < 4; ++r) {
                float om1 = __shfl_xor(rm1[m][r], off);
                float om2 = __shfl_xor(rm2[m][r], off);
                int   oi  = __shfl_xor(ri1[m][r], off);
                if (om1 > rm1[m][r] || (om1 == rm1[m][r] && oi < ri1[m][r])) {
                    rm2[m][r] = fmaxf(rm1[m][r], om2); rm1[m][r] = om1; ri1[m][r] = oi;
                } else {
                    rm2[m][r] = fmaxf(rm2[m][r], om1);
                }
            }
    }
    if ((l & 15) == 0) {
        #pragma unroll
        for (int m = 0; m < 4; ++m)
            #pragma unroll
            for (int r = 0; r < 4; ++r) {
                int row = wr * 64 + m * 16 + (l >> 4) * 4 + r;
                sm1[wc][row] = rm1[m][r]; sm2[wc][row] = rm2[m][r]; si1[wc][row] = ri1[m][r];
            }
    }
    __syncthreads();
    if (tid < 128) {
        float m1 = sm1[0][tid], m2 = sm2[0][tid]; int i1 = si1[0][tid];
        #pragma unroll
        for (int q = 1; q < 4; ++q) {
            float om1 = sm1[q][tid], om2 = sm2[q][tid]; int oi = si1[q][tid];
            if (om1 > m1 || (om1 == m1 && oi < i1)) { m2 = fmaxf(m1, om2); m1 = om1; i1 = oi; }
            else m2 = fmaxf(m2, om1);
        }
        pm1[(size_t)ct * NR + n0 + tid] = m1;
        pm2[(size_t)ct * NR + n0 + tid] = m2;
        pi1[(size_t)ct * NR + n0 + tid] = i1;
    }
}

// merge 32 col-tile partials per row -> ids + near-tie flags
__global__ void k_merge(const float* __restrict__ pm1, const float* __restrict__ pm2,
                        const int* __restrict__ pi1, int* __restrict__ ids,
                        int* __restrict__ flag_cnt, int* __restrict__ flag_list) {
    int row = blockIdx.x * 256 + threadIdx.x;
    float m1 = -3.4e38f, m2 = -3.4e38f; int i1 = 0x7fffffff;
    for (int j = 0; j < 32; ++j) {
        float om1 = pm1[(size_t)j * NR + row];
        float om2 = pm2[(size_t)j * NR + row];
        int   oi  = pi1[(size_t)j * NR + row];
        if (om1 > m1 || (om1 == m1 && oi < i1)) { m2 = fmaxf(m1, om2); m1 = om1; i1 = oi; }
        else m2 = fmaxf(m2, om1);
    }
    ids[row] = i1;
    if (m1 - m2 < 2e-4f) {
        int p = atomicAdd(flag_cnt, 1);
        flag_list[p] = row;
    }
}

// numpy-fp32-path emulation for near-tie rows (validated in round 2)
__global__ __launch_bounds__(256) void k_rescore(
    const float* __restrict__ x, const float* __restrict__ embedT,
    const float* __restrict__ e2np, const int* __restrict__ flag_cnt,
    const int* __restrict__ flag_list, int* __restrict__ ids)
{
    __shared__ float row[256];
    __shared__ float sq[256];
    __shared__ float bdA[256];
    __shared__ int   biA[256];
    const int tid = threadIdx.x;
    const int cnt = *flag_cnt;
    for (int f = blockIdx.x; f < cnt; f += gridDim.x) {
        const int n = flag_list[f];
        const int b = n >> 10, wq = (n >> 5) & 31, hq = n & 31;
        const float v = x[((size_t)(b * 256 + tid)) * 1024 + hq * 32 + wq];
        row[tid] = v;
        sq[tid] = v * v;              // rounds at LDS store
        __syncthreads();
        const float x2 = np_pw128(sq) + np_pw128(sq + 128);

        float acc[32];
        #pragma unroll
        for (int j = 0; j < 32; ++j) acc[j] = 0.0f;
        for (int c = 0; c < 256; ++c) {
            const float av = row[c];
            const float* bp = embedT + (size_t)c * KD + tid * 4;
            #pragma unroll
            for (int j2 = 0; j2 < 8; ++j2) {
                const float4 bv = *(const float4*)(bp + j2 * 1024);
                acc[j2 * 4 + 0] = fmaf(av, bv.x, acc[j2 * 4 + 0]);
                acc[j2 * 4 + 1] = fmaf(av, bv.y, acc[j2 * 4 + 1]);
                acc[j2 * 4 + 2] = fmaf(av, bv.z, acc[j2 * 4 + 2]);
                acc[j2 * 4 + 3] = fmaf(av, bv.w, acc[j2 * 4 + 3]);
            }
        }
        float bd = 3.4e38f; int bi = 0x7fffffff;
        #pragma unroll
        for (int j2 = 0; j2 < 8; ++j2) {
            #pragma unroll
            for (int e = 0; e < 4; ++e) {
                const int k = j2 * 1024 + tid * 4 + e;
                const float d2 = (x2 - 2.0f * acc[j2 * 4 + e]) + e2np[k];
                if (d2 < bd || (d2 == bd && k < bi)) { bd = d2; bi = k; }
            }
        }
        bdA[tid] = bd; biA[tid] = bi;
        __syncthreads();
        if (tid == 0) {
            float bb = bdA[0]; int j1 = biA[0];
            for (int i = 1; i < 256; ++i) {
                if (bdA[i] < bb || (bdA[i] == bb && biA[i] < j1)) { bb = bdA[i]; j1 = biA[i]; }
            }
            ids[n] = j1;
        }
        __syncthreads();
    }
}

// st_out (= vqs) + loss partial sums
__global__ void k_output(const float* __restrict__ x, const float* __restrict__ embed,
                         const int* __restrict__ ids, float* __restrict__ st,
                         float* __restrict__ loss_ws)
{
    const size_t base = ((size_t)blockIdx.x * 256 + threadIdx.x) * 4;
    const int w = (int)(base & 31);
    const int h = (int)((base >> 5) & 31);
    const int c = (int)((base >> 10) & 255);
    const int b = (int)(base >> 18);
    const float4 xv = *(const float4*)(x + base);
    const int nb = b * 1024 + h;
    const float vq0 = embed[(size_t)ids[nb + (w + 0) * 32] * CD + c];
    const float vq1 = embed[(size_t)ids[nb + (w + 1) * 32] * CD + c];
    const float vq2 = embed[(size_t)ids[nb + (w + 2) * 32] * CD + c];
    const float vq3 = embed[(size_t)ids[nb + (w + 3) * 32] * CD + c];
    *(float4*)(st + base) = make_float4(vq0, vq1, vq2, vq3);
    const float d0 = vq0 - xv.x, d1 = vq1 - xv.y, d2 = vq2 - xv.z, d3 = vq3 - xv.w;
    float s = d0 * d0 + d1 * d1 + d2 * d2 + d3 * d3;
    #pragma unroll
    for (int off = 1; off < 64; off <<= 1) s += __shfl_xor(s, off);
    if ((threadIdx.x & 63) == 0) atomicAdd(loss_ws, s);
}

__global__ void k_ids(const int* __restrict__ ids, float* __restrict__ ids_out) {
    int e = blockIdx.x * 256 + threadIdx.x;
    int b = e >> 10, h = (e >> 5) & 31, w = e & 31;
    ids_out[e] = (float)ids[b * 1024 + w * 32 + h];
}

__global__ void k_counti(const int* __restrict__ ids, int* __restrict__ counts) {
    int n = blockIdx.x * 256 + threadIdx.x;
    atomicAdd(&counts[ids[n]], 1);
}

__global__ void k_scan(const int* __restrict__ counts, int* __restrict__ offs,
                       float* __restrict__ track_num) {
    __shared__ int ps[257];
    const int tid = threadIdx.x;
    int loc[32]; int s = 0;
    const int base = tid * 32;
    #pragma unroll
    for (int j = 0; j < 32; ++j) { loc[j] = s; s += counts[base + j]; }
    ps[tid + 1] = s;
    if (tid == 0) ps[0] = 0;
    __syncthreads();
    if (tid == 0) for (int i = 1; i <= 256; ++i) ps[i] += ps[i - 1];
    __syncthreads();
    const int pre = ps[tid];
    #pragma unroll
    for (int j = 0; j < 32; ++j) {
        offs[base + j] = pre + loc[j];
        track_num[base + j] = (float)counts[base + j];
    }
}

__global__ void k_fill(const int* __restrict__ ids, const int* __restrict__ offs,
                       int* __restrict__ cursor, int* __restrict__ bucket) {
    int n = blockIdx.x * 256 + threadIdx.x;
    int id = ids[n];
    int p = atomicAdd(&cursor[id], 1);
    bucket[offs[id] + p] = n;
}

// track_enc[k][c] = sum over bucket rows of (a_hi + a_lo)  (no atomics)
__global__ void k_gather(const __bf16* __restrict__ aH, const __bf16* __restrict__ aL,
                         const int* __restrict__ offs, const int* __restrict__ counts,
                         const int* __restrict__ bucket, float* __restrict__ enc) {
    const int k = blockIdx.x, c = threadIdx.x;
    const int o = offs[k], cnt = counts[k];
    float s = 0.f;
    for (int i = 0; i < cnt; ++i) {
        int n = bucket[o + i];
        s += (float)aH[(size_t)n * CD + c] + (float)aL[(size_t)n * CD + c];
    }
    enc[(size_t)k * CD + c] = s;
}

__global__ void k_final(const float* __restrict__ track_num, const float* __restrict__ track_enc,
                        float* __restrict__ new_embed, const float* __restrict__ loss_ws,
                        float* __restrict__ loss_out)
{
    const size_t e = (size_t)blockIdx.x * 256 + threadIdx.x;
    const int k = (int)(e >> 8);
    const float factor = 1.0f + (1e-5f * 8192.0f) / 32768.0f;
    new_embed[e] = track_enc[e] * factor / (track_num[k] + 1e-5f);
    if (e == 0) loss_out[0] = loss_ws[0] * (1.0f / 8388608.0f);
}

extern "C" void kernel_launch(void* const* d_in, const int* in_sizes, int n_in,
                              void* d_out, int out_size, void* d_ws, size_t ws_size,
                              hipStream_t stream)
{
    const float* x     = (const float*)d_in[0];
    const float* embed = (const float*)d_in[1];
    float* out = (float*)d_out;
    float* ws  = (float*)d_ws;

    __bf16* aH = (__bf16*)(ws + F_AH);
    __bf16* aL = (__bf16*)(ws + F_AL);
    __bf16* bH = (__bf16*)(ws + F_BH);
    __bf16* bL = (__bf16*)(ws + F_BL);
    float* embedT    = ws + F_EMBT;
    float* pm1       = ws + F_PM1;
    float* pm2       = ws + F_PM2;
    int*   pi1       = (int*)(ws + F_PI1);
    float* e2        = ws + F_E2;
    float* e2np      = ws + F_E2NP;
    int*   ids       = (int*)(ws + F_IDS);
    int*   flag_cnt  = (int*)(ws + F_FLAGCNT);
    float* loss_ws   = ws + F_LOSS;
    int*   flag_list = (int*)(ws + F_FLAGLST);
    int*   counts    = (int*)(ws + F_COUNTS);
    int*   cursor    = (int*)(ws + F_CURSOR);
    int*   offs      = (int*)(ws + F_OFFS);
    int*   bucket    = (int*)(ws + F_BUCKET);

    hipMemsetAsync(ws + F_FLAGCNT, 0, 2 * sizeof(float), stream);          // flag_cnt + loss
    hipMemsetAsync(ws + F_COUNTS, 0, 2 * 8192 * sizeof(float), stream);    // counts + cursor

    k_cvt_x  <<<512,  256, 0, stream>>>(x, aH, aL);
    k_cvt_e  <<<2048, 256, 0, stream>>>(embed, bH, bL);
    k_e2     <<<2048, 256, 0, stream>>>(embed, e2);
    k_e2np   <<<256,  256, 0, stream>>>(embed, e2np);
    k_epose  <<<512,  256, 0, stream>>>(embed, embedT);
    k_mfma   <<<8192, 512, 0, stream>>>(aH, aL, bH, bL, e2, pm1, pm2, pi1);
    k_merge  <<<128,  256, 0, stream>>>(pm1, pm2, pi1, ids, flag_cnt, flag_list);
    k_rescore<<<256,  256, 0, stream>>>(x, embedT, e2np, flag_cnt, flag_list, ids);
    k_output <<<8192, 256, 0, stream>>>(x, embed, ids, out + OUT_ST, loss_ws);
    k_ids    <<<128,  256, 0, stream>>>(ids, out + OUT_IDS);
    k_counti <<<128,  256, 0, stream>>>(ids, counts);
    k_scan   <<<1,    256, 0, stream>>>(counts, offs, out + OUT_NUM);
    k_fill   <<<128,  256, 0, stream>>>(ids, offs, cursor, bucket);
    k_gather <<<8192, 256, 0, stream>>>(aH, aL, offs, counts, bucket, out + OUT_ENC);
    k_final  <<<8192, 256, 0, stream>>>(out + OUT_NUM, out + OUT_ENC, out + OUT_NEMB,
                                        loss_ws, out + OUT_LOSS);
}

// Round 4
// 1065.008 us; speedup vs baseline: 4.5716x; 1.6258x over previous
//
#include <hip/hip_runtime.h>

#define NR 32768   // rows (b*w*h)
#define CD 256     // emb dim
#define KD 8192    // dict size

typedef __attribute__((ext_vector_type(8))) _Float16 f16x8;
typedef __attribute__((ext_vector_type(4))) _Float16 f16x4;
typedef __attribute__((ext_vector_type(4))) float f32x4;

// ---- workspace float offsets ----
#define F_XH      0ull          // f16[32768][256] hi  (16MB)
#define F_XL      4194304ull    // f16[32768][256] lo  (16MB)
#define F_EH      8388608ull    // f16[8192][256] hi   (4MB)
#define F_EMBT    9437184ull    // fp32 embedT[256][8192] (8MB, rescore)
#define F_PM1     11534336ull   // f32 [32][32768]
#define F_PM2     12582912ull
#define F_PI1     13631488ull
#define F_E2      14680064ull   // 8192
#define F_E2NP    14688256ull   // 8192
#define F_IDS     14696448ull   // 32768 ints
#define F_FLAGCNT 14729216ull
#define F_LOSS    14729217ull
#define F_FLAGLST 14729218ull   // up to 32768 ints
#define F_COUNTS  14761986ull   // 8192 ints
#define F_CURSOR  14770178ull   // 8192 ints
#define F_OFFS    14778370ull   // 8192 ints
#define F_BUCKET  14786562ull   // 32768 ints
#define F_PBD     14819330ull   // 4096*8 floats
#define F_PBI     14852098ull   // 4096*8 ints

// ---- output float offsets ----
#define OUT_ST   0ull
#define OUT_LOSS 8388608ull
#define OUT_IDS  8388609ull
#define OUT_NEMB 8421377ull
#define OUT_NUM  10518529ull
#define OUT_ENC  10526721ull

// numpy pairwise_sum for a 128-block: 8 accumulators, fixed combine tree.
__device__ __forceinline__ float np_pw128(const float* p) {
    float r0 = p[0], r1 = p[1], r2 = p[2], r3 = p[3];
    float r4 = p[4], r5 = p[5], r6 = p[6], r7 = p[7];
    for (int i = 8; i < 128; i += 8) {
        r0 += p[i + 0]; r1 += p[i + 1]; r2 += p[i + 2]; r3 += p[i + 3];
        r4 += p[i + 4]; r5 += p[i + 5]; r6 += p[i + 6]; r7 += p[i + 7];
    }
    return ((r0 + r1) + (r2 + r3)) + ((r4 + r5) + (r6 + r7));
}

// x (b,c,h,w) -> xh/xl[n][c] f16 split, n = b*1024 + w*32 + h
__global__ void k_cvt_x(const float* __restrict__ x,
                        _Float16* __restrict__ xh, _Float16* __restrict__ xl) {
    __shared__ float t[32 * 529];   // [c32][h16*33 + w]
    const int bx = blockIdx.x;
    const int b = bx >> 4, cg = (bx >> 1) & 7, h0 = (bx & 1) * 16;
    const int tid = threadIdx.x;
    const float* src = x + ((size_t)(b * 256 + cg * 32)) * 1024 + h0 * 32;
    for (int i = 0; i < 64; ++i) {
        int e = i * 256 + tid;
        int c = e >> 9, rem = e & 511;
        int hh = rem >> 5, w = rem & 31;
        t[c * 529 + hh * 33 + w] = src[(size_t)c * 1024 + hh * 32 + w];
    }
    __syncthreads();
    const int ni = tid >> 5, c = tid & 31;
    for (int i = 0; i < 64; ++i) {
        int ns = i * 8 + ni;             // 0..511 = w*16 + hh
        int w = ns >> 4, hh = ns & 15;
        float v = t[c * 529 + hh * 33 + w];
        _Float16 hi = (_Float16)v;
        _Float16 lo = (_Float16)(v - (float)hi);
        size_t o = ((size_t)(b * 1024 + w * 32 + h0 + hh)) * 256 + cg * 32 + c;
        xh[o] = hi; xl[o] = lo;
    }
}

// embed -> eh f16 (hi only) + fast e2
__global__ void k_prep_e(const float* __restrict__ embed,
                         _Float16* __restrict__ eh, float* __restrict__ e2) {
    int wave = threadIdx.x >> 6, lane = threadIdx.x & 63;
    int k = blockIdx.x * 4 + wave;
    float4 v = *(const float4*)(embed + (size_t)k * CD + lane * 4);
    f16x4 h;
    h[0] = (_Float16)v.x; h[1] = (_Float16)v.y;
    h[2] = (_Float16)v.z; h[3] = (_Float16)v.w;
    *(f16x4*)&eh[(size_t)k * CD + lane * 4] = h;
    float s = v.x * v.x + v.y * v.y + v.z * v.z + v.w * v.w;
    #pragma unroll
    for (int off = 1; off < 64; off <<= 1) s += __shfl_xor(s, off);
    if (lane == 0) e2[k] = s;
}

// numpy-emulated e2, wave-parallel: 8 lanes per k, exact pairwise tree.
__global__ void k_e2np(const float* __restrict__ embed, float* __restrict__ e2np) {
    const int lane = threadIdx.x & 63;
    const int wv = threadIdx.x >> 6;
    const int k = blockIdx.x * 32 + wv * 8 + (lane >> 3);
    const int j = lane & 7;
    float hsum[2];
    #pragma unroll
    for (int half = 0; half < 2; ++half) {
        float r = 0.f;
        for (int i = 0; i < 16; ++i) {
            float v = embed[(size_t)k * CD + half * 128 + j + i * 8];
            float sq = v * v;
            asm volatile("" : "+v"(sq));   // round v*v to fp32 (block contraction)
            r += sq;
        }
        float s = r + __shfl_xor(r, 1);
        s = s + __shfl_xor(s, 2);
        s = s + __shfl_xor(s, 4);
        hsum[half] = s;
    }
    if (j == 0) e2np[k] = hsum[0] + hsum[1];
}

// embed (k,c) -> embedT[c][k] fp32 (rescore only)
__global__ void k_epose(const float* __restrict__ embed, float* __restrict__ embedT) {
    int kt = blockIdx.x >> 2, ct = blockIdx.x & 3;
    __shared__ float t[64][65];
    int tid = threadIdx.x;
    #pragma unroll
    for (int i = 0; i < 16; ++i) {
        int e = tid + i * 256; int r = e >> 6, c = e & 63;
        t[r][c] = embed[(size_t)(kt * 64 + r) * CD + ct * 64 + c];
    }
    __syncthreads();
    #pragma unroll
    for (int i = 0; i < 16; ++i) {
        int e = tid + i * 256; int c = e >> 6, r = e & 63;
        embedT[(size_t)(ct * 64 + c) * KD + kt * 64 + r] = t[r][c];
    }
}

// MFMA argmin: single-pass f16 GEMM, block 256x256, 8 waves (2x4), wave 128x64.
// LDS tiles swizzled (slot ^= (row>>1)&3, both staging-source and read side).
__global__ __launch_bounds__(512, 2) void k_mfma(
    const _Float16* __restrict__ xh, const _Float16* __restrict__ eh,
    const float* __restrict__ e2,
    float* __restrict__ pm1, float* __restrict__ pm2, int* __restrict__ pi1)
{
    __shared__ _Float16 lds[2][16384];   // per buf: A[256][32] f16, B[256][32] f16
    __shared__ float sm1[4][256], sm2[4][256];
    __shared__ int   si1[4][256];
    const int tid = threadIdx.x;
    const int w = tid >> 6, l = tid & 63;
    const int logical = (blockIdx.x & 7) * 512 + (blockIdx.x >> 3);  // XCD chunk
    const int ct = logical & 31, rt = logical >> 5;
    const int n0 = rt * 256, k0 = ct * 256;
    const int wr = w >> 2, wc = w & 3;

    f32x4 acc[8][4];
    #pragma unroll
    for (int m = 0; m < 8; ++m)
        #pragma unroll
        for (int n = 0; n < 4; ++n)
            acc[m][n] = (f32x4){0.f, 0.f, 0.f, 0.f};

    const int lrow = l >> 2, lslot = l & 3;
    const int sslot = lslot ^ ((lrow >> 1) & 3);   // pre-swizzled source slot

    auto STAGE = [&](int buf, int t) {
        const int scol = t * 32 + sslot * 8;
        #pragma unroll
        for (int jj = 0; jj < 4; ++jj) {
            const int j = (w & 3) * 4 + jj;        // 16-row block within region
            const _Float16* src;
            unsigned loff;
            if (w < 4) { src = xh + ((size_t)(n0 + j * 16 + lrow)) * 256 + scol; loff = (unsigned)j * 512; }
            else       { src = eh + ((size_t)(k0 + j * 16 + lrow)) * 256 + scol; loff = 8192u + (unsigned)j * 512; }
            __builtin_amdgcn_global_load_lds(
                (const __attribute__((address_space(1))) unsigned int*)src,
                (__attribute__((address_space(3))) unsigned int*)&lds[buf][loff],
                16, 0, 0);
        }
    };

    const int lr = l & 15, lsl = l >> 4;
    const int rslot = (lsl ^ ((lr >> 1) & 3)) * 8;   // swizzled read slot

    auto COMPUTE = [&](int buf) {
        f16x8 fa[8], fb[4];
        #pragma unroll
        for (int m = 0; m < 8; ++m) {
            int j = wr * 8 + m;
            fa[m] = *(const f16x8*)&lds[buf][j * 512 + lr * 32 + rslot];
        }
        #pragma unroll
        for (int n = 0; n < 4; ++n) {
            int j = wc * 4 + n;
            fb[n] = *(const f16x8*)&lds[buf][8192 + j * 512 + lr * 32 + rslot];
        }
        #pragma unroll
        for (int m = 0; m < 8; ++m)
            #pragma unroll
            for (int n = 0; n < 4; ++n)
                acc[m][n] = __builtin_amdgcn_mfma_f32_16x16x32_f16(fa[m], fb[n], acc[m][n], 0, 0, 0);
    };

    STAGE(0, 0);
    __syncthreads();
    int cur = 0;
    for (int t = 0; t < 8; ++t) {
        if (t < 7) STAGE(cur ^ 1, t + 1);
        COMPUTE(cur);
        __syncthreads();
        cur ^= 1;
    }

    // epilogue: score = acc - 0.5*e2; per-row top-2 within this 256-col tile
    float e2v[4];
    #pragma unroll
    for (int n = 0; n < 4; ++n) e2v[n] = e2[k0 + wc * 64 + n * 16 + (l & 15)];
    #pragma unroll
    for (int m = 0; m < 8; ++m) {
        float rm1[4], rm2[4]; int ri1[4];
        #pragma unroll
        for (int r = 0; r < 4; ++r) {
            float m1 = -3.4e38f, m2 = -3.4e38f; int i1 = 0;
            #pragma unroll
            for (int n = 0; n < 4; ++n) {
                float v = acc[m][n][r] - 0.5f * e2v[n];
                int kk = k0 + wc * 64 + n * 16 + (l & 15);
                if (v > m1)      { m2 = m1; m1 = v; i1 = kk; }
                else if (v > m2) { m2 = v; }
            }
            rm1[r] = m1; rm2[r] = m2; ri1[r] = i1;
        }
        #pragma unroll
        for (int off = 1; off < 16; off <<= 1) {
            #pragma unroll
            for (int r = 0; r < 4; ++r) {
                float om1 = __shfl_xor(rm1[r], off);
                float om2 = __shfl_xor(rm2[r], off);
                int   oi  = __shfl_xor(ri1[r], off);
                if (om1 > rm1[r] || (om1 == rm1[r] && oi < ri1[r])) {
                    rm2[r] = fmaxf(rm1[r], om2); rm1[r] = om1; ri1[r] = oi;
                } else {
                    rm2[r] = fmaxf(rm2[r], om1);
                }
            }
        }
        if ((l & 15) == 0) {
            #pragma unroll
            for (int r = 0; r < 4; ++r) {
                int row = wr * 128 + m * 16 + (l >> 4) * 4 + r;
                sm1[wc][row] = rm1[r]; sm2[wc][row] = rm2[r]; si1[wc][row] = ri1[r];
            }
        }
    }
    __syncthreads();
    if (tid < 256) {
        float m1 = sm1[0][tid], m2 = sm2[0][tid]; int i1 = si1[0][tid];
        #pragma unroll
        for (int q = 1; q < 4; ++q) {
            float om1 = sm1[q][tid], om2 = sm2[q][tid]; int oi = si1[q][tid];
            if (om1 > m1 || (om1 == m1 && oi < i1)) { m2 = fmaxf(m1, om2); m1 = om1; i1 = oi; }
            else m2 = fmaxf(m2, om1);
        }
        pm1[(size_t)ct * NR + n0 + tid] = m1;
        pm2[(size_t)ct * NR + n0 + tid] = m2;
        pi1[(size_t)ct * NR + n0 + tid] = i1;
    }
}

// merge 32 col-tile partials per row -> ids + near-tie flags
__global__ void k_merge(const float* __restrict__ pm1, const float* __restrict__ pm2,
                        const int* __restrict__ pi1, int* __restrict__ ids,
                        int* __restrict__ flag_cnt, int* __restrict__ flag_list) {
    int row = blockIdx.x * 256 + threadIdx.x;
    float m1 = -3.4e38f, m2 = -3.4e38f; int i1 = 0x7fffffff;
    for (int j = 0; j < 32; ++j) {
        float om1 = pm1[(size_t)j * NR + row];
        float om2 = pm2[(size_t)j * NR + row];
        int   oi  = pi1[(size_t)j * NR + row];
        if (om1 > m1 || (om1 == m1 && oi < i1)) { m2 = fmaxf(m1, om2); m1 = om1; i1 = oi; }
        else m2 = fmaxf(m2, om1);
    }
    ids[row] = i1;
    if (m1 - m2 < 2.5e-3f) {           // ~19 sigma of f16 single-pass dot error
        int p = atomicAdd(flag_cnt, 1);
        flag_list[p] = row;
    }
}

// batched numpy-fp32-path rescore: 8 rows/group x 8 k-slices (kt) per block.
#define RG 8
__global__ __launch_bounds__(256) void k_rescore(
    const float* __restrict__ x, const float* __restrict__ embedT,
    const float* __restrict__ e2np, const int* __restrict__ flag_cnt,
    const int* __restrict__ flag_list, float* __restrict__ pbd, int* __restrict__ pbi)
{
    __shared__ float rowl[RG][256];
    __shared__ float sq[RG][256];
    __shared__ float x2s[RG];
    __shared__ float bdA[256];
    __shared__ int   biA[256];
    const int tid = threadIdx.x;
    int cnt = *flag_cnt; if (cnt > 4096) cnt = 4096;
    const int ngroups = (cnt + RG - 1) / RG;
    const int kt = blockIdx.x & 7;
    for (int g = blockIdx.x >> 3; g < ngroups; g += 64) {
        #pragma unroll
        for (int i = 0; i < RG; ++i) {
            int f = g * RG + i;
            float v = 0.f;
            if (f < cnt) {
                int n = flag_list[f];
                int b = n >> 10, wq = (n >> 5) & 31, hq = n & 31;
                v = x[((size_t)(b * 256 + tid)) * 1024 + hq * 32 + wq];
            }
            rowl[i][tid] = v;
            sq[i][tid] = v * v;       // product rounds at LDS store
        }
        __syncthreads();
        if (tid < RG) x2s[tid] = np_pw128(sq[tid]) + np_pw128(sq[tid] + 128);
        __syncthreads();

        float acc[RG][4];
        #pragma unroll
        for (int r = 0; r < RG; ++r)
            #pragma unroll
            for (int e = 0; e < 4; ++e) acc[r][e] = 0.f;
        for (int c = 0; c < 256; ++c) {
            const f32x4 bv = *(const f32x4*)&embedT[(size_t)c * KD + kt * 1024 + tid * 4];
            #pragma unroll
            for (int r = 0; r < RG; ++r) {
                const float av = rowl[r][c];
                acc[r][0] = fmaf(av, bv[0], acc[r][0]);
                acc[r][1] = fmaf(av, bv[1], acc[r][1]);
                acc[r][2] = fmaf(av, bv[2], acc[r][2]);
                acc[r][3] = fmaf(av, bv[3], acc[r][3]);
            }
        }
        float bd[RG]; int bi[RG];
        #pragma unroll
        for (int r = 0; r < RG; ++r) {
            bd[r] = 3.4e38f; bi[r] = 0x7fffffff;
            #pragma unroll
            for (int e = 0; e < 4; ++e) {
                const int k = kt * 1024 + tid * 4 + e;
                const float d2 = (x2s[r] - 2.0f * acc[r][e]) + e2np[k];
                if (d2 < bd[r] || (d2 == bd[r] && k < bi[r])) { bd[r] = d2; bi[r] = k; }
            }
        }
        #pragma unroll
        for (int r = 0; r < RG; ++r) {
            bdA[tid] = bd[r]; biA[tid] = bi[r];
            __syncthreads();
            for (int off = 128; off > 0; off >>= 1) {
                if (tid < off) {
                    float od = bdA[tid + off]; int oi = biA[tid + off];
                    if (od < bdA[tid] || (od == bdA[tid] && oi < biA[tid])) {
                        bdA[tid] = od; biA[tid] = oi;
                    }
                }
                __syncthreads();
            }
            if (tid == 0) {
                int f = g * RG + r;
                pbd[f * 8 + kt] = bdA[0]; pbi[f * 8 + kt] = biA[0];
            }
            __syncthreads();
        }
    }
}

__global__ void k_flagmerge(const int* __restrict__ flag_cnt, const int* __restrict__ flag_list,
                            const float* __restrict__ pbd, const int* __restrict__ pbi,
                            int* __restrict__ ids) {
    int cnt = *flag_cnt; if (cnt > 4096) cnt = 4096;
    int f = blockIdx.x * 256 + threadIdx.x;
    if (f >= cnt) return;
    float bd = pbd[f * 8]; int bi = pbi[f * 8];
    #pragma unroll
    for (int kt = 1; kt < 8; ++kt) {
        float d = pbd[f * 8 + kt]; int i = pbi[f * 8 + kt];
        if (d < bd || (d == bd && i < bi)) { bd = d; bi = i; }
    }
    ids[flag_list[f]] = bi;
}

// st_out (= vqs) + loss partial sums
__global__ void k_output(const float* __restrict__ x, const float* __restrict__ embed,
                         const int* __restrict__ ids, float* __restrict__ st,
                         float* __restrict__ loss_ws)
{
    const size_t base = ((size_t)blockIdx.x * 256 + threadIdx.x) * 4;
    const int w = (int)(base & 31);
    const int h = (int)((base >> 5) & 31);
    const int c = (int)((base >> 10) & 255);
    const int b = (int)(base >> 18);
    const float4 xv = *(const float4*)(x + base);
    const int nb = b * 1024 + h;
    const float vq0 = embed[(size_t)ids[nb + (w + 0) * 32] * CD + c];
    const float vq1 = embed[(size_t)ids[nb + (w + 1) * 32] * CD + c];
    const float vq2 = embed[(size_t)ids[nb + (w + 2) * 32] * CD + c];
    const float vq3 = embed[(size_t)ids[nb + (w + 3) * 32] * CD + c];
    *(float4*)(st + base) = make_float4(vq0, vq1, vq2, vq3);
    const float d0 = vq0 - xv.x, d1 = vq1 - xv.y, d2 = vq2 - xv.z, d3 = vq3 - xv.w;
    float s = d0 * d0 + d1 * d1 + d2 * d2 + d3 * d3;
    #pragma unroll
    for (int off = 1; off < 64; off <<= 1) s += __shfl_xor(s, off);
    if ((threadIdx.x & 63) == 0) atomicAdd(loss_ws, s);
}

__global__ void k_ids(const int* __restrict__ ids, float* __restrict__ ids_out) {
    int e = blockIdx.x * 256 + threadIdx.x;
    int b = e >> 10, h = (e >> 5) & 31, w = e & 31;
    ids_out[e] = (float)ids[b * 1024 + w * 32 + h];
}

__global__ void k_counti(const int* __restrict__ ids, int* __restrict__ counts) {
    int n = blockIdx.x * 256 + threadIdx.x;
    atomicAdd(&counts[ids[n]], 1);
}

__global__ void k_scan(const int* __restrict__ counts, int* __restrict__ offs,
                       float* __restrict__ track_num) {
    __shared__ int ps[257];
    const int tid = threadIdx.x;
    int loc[32]; int s = 0;
    const int base = tid * 32;
    #pragma unroll
    for (int j = 0; j < 32; ++j) { loc[j] = s; s += counts[base + j]; }
    ps[tid + 1] = s;
    if (tid == 0) ps[0] = 0;
    __syncthreads();
    if (tid == 0) for (int i = 1; i <= 256; ++i) ps[i] += ps[i - 1];
    __syncthreads();
    const int pre = ps[tid];
    #pragma unroll
    for (int j = 0; j < 32; ++j) {
        offs[base + j] = pre + loc[j];
        track_num[base + j] = (float)counts[base + j];
    }
}

__global__ void k_fill(const int* __restrict__ ids, const int* __restrict__ offs,
                       int* __restrict__ cursor, int* __restrict__ bucket) {
    int n = blockIdx.x * 256 + threadIdx.x;
    int id = ids[n];
    int p = atomicAdd(&cursor[id], 1);
    bucket[offs[id] + p] = n;
}

// track_enc[k][c] = sum over bucket rows of (xh + xl)  (no atomics)
__global__ void k_gather(const _Float16* __restrict__ xh, const _Float16* __restrict__ xl,
                         const int* __restrict__ offs, const int* __restrict__ counts,
                         const int* __restrict__ bucket, float* __restrict__ enc) {
    const int k = blockIdx.x, c = threadIdx.x;
    const int o = offs[k], cnt = counts[k];
    float s = 0.f;
    for (int i = 0; i < cnt; ++i) {
        int n = bucket[o + i];
        s += (float)xh[(size_t)n * CD + c] + (float)xl[(size_t)n * CD + c];
    }
    enc[(size_t)k * CD + c] = s;
}

__global__ void k_final(const float* __restrict__ track_num, const float* __restrict__ track_enc,
                        float* __restrict__ new_embed, const float* __restrict__ loss_ws,
                        float* __restrict__ loss_out)
{
    const size_t e = (size_t)blockIdx.x * 256 + threadIdx.x;
    const int k = (int)(e >> 8);
    const float factor = 1.0f + (1e-5f * 8192.0f) / 32768.0f;
    new_embed[e] = track_enc[e] * factor / (track_num[k] + 1e-5f);
    if (e == 0) loss_out[0] = loss_ws[0] * (1.0f / 8388608.0f);
}

extern "C" void kernel_launch(void* const* d_in, const int* in_sizes, int n_in,
                              void* d_out, int out_size, void* d_ws, size_t ws_size,
                              hipStream_t stream)
{
    const float* x     = (const float*)d_in[0];
    const float* embed = (const float*)d_in[1];
    float* out = (float*)d_out;
    float* ws  = (float*)d_ws;

    _Float16* xh = (_Float16*)(ws + F_XH);
    _Float16* xl = (_Float16*)(ws + F_XL);
    _Float16* eh = (_Float16*)(ws + F_EH);
    float* embedT    = ws + F_EMBT;
    float* pm1       = ws + F_PM1;
    float* pm2       = ws + F_PM2;
    int*   pi1       = (int*)(ws + F_PI1);
    float* e2        = ws + F_E2;
    float* e2np      = ws + F_E2NP;
    int*   ids       = (int*)(ws + F_IDS);
    int*   flag_cnt  = (int*)(ws + F_FLAGCNT);
    float* loss_ws   = ws + F_LOSS;
    int*   flag_list = (int*)(ws + F_FLAGLST);
    int*   counts    = (int*)(ws + F_COUNTS);
    int*   cursor    = (int*)(ws + F_CURSOR);
    int*   offs      = (int*)(ws + F_OFFS);
    int*   bucket    = (int*)(ws + F_BUCKET);
    float* pbd       = ws + F_PBD;
    int*   pbi       = (int*)(ws + F_PBI);

    hipMemsetAsync(ws + F_FLAGCNT, 0, 2 * sizeof(float), stream);          // flag_cnt + loss
    hipMemsetAsync(ws + F_COUNTS, 0, 2 * 8192 * sizeof(float), stream);    // counts + cursor

    k_cvt_x    <<<512,  256, 0, stream>>>(x, xh, xl);
    k_prep_e   <<<2048, 256, 0, stream>>>(embed, eh, e2);
    k_e2np     <<<256,  256, 0, stream>>>(embed, e2np);
    k_epose    <<<512,  256, 0, stream>>>(embed, embedT);
    k_mfma     <<<4096, 512, 0, stream>>>(xh, eh, e2, pm1, pm2, pi1);
    k_merge    <<<128,  256, 0, stream>>>(pm1, pm2, pi1, ids, flag_cnt, flag_list);
    k_rescore  <<<512,  256, 0, stream>>>(x, embedT, e2np, flag_cnt, flag_list, pbd, pbi);
    k_flagmerge<<<16,   256, 0, stream>>>(flag_cnt, flag_list, pbd, pbi, ids);
    k_output   <<<8192, 256, 0, stream>>>(x, embed, ids, out + OUT_ST, loss_ws);
    k_ids      <<<128,  256, 0, stream>>>(ids, out + OUT_IDS);
    k_counti   <<<128,  256, 0, stream>>>(ids, counts);
    k_scan     <<<1,    256, 0, stream>>>(counts, offs, out + OUT_NUM);
    k_fill     <<<128,  256, 0, stream>>>(ids, offs, cursor, bucket);
    k_gather   <<<8192, 256, 0, stream>>>(xh, xl, offs, counts, bucket, out + OUT_ENC);
    k_final    <<<8192, 256, 0, stream>>>(out + OUT_NUM, out + OUT_ENC, out + OUT_NEMB,
                                          loss_ws, out + OUT_LOSS);
}

// Round 5
// 823.106 us; speedup vs baseline: 5.9151x; 1.2939x over previous
//
#include <hip/hip_runtime.h>

#define NR 32768   // rows (b*w*h)
#define CD 256     // emb dim
#define KD 8192    // dict size

typedef __attribute__((ext_vector_type(8))) _Float16 f16x8;
typedef __attribute__((ext_vector_type(4))) _Float16 f16x4;
typedef __attribute__((ext_vector_type(4))) float f32x4;

// ---- workspace float offsets ----
#define F_XH      0ull          // f16[32768][256] hi  (16MB)
#define F_XL      4194304ull    // f16[32768][256] lo  (16MB)
#define F_EH      8388608ull    // f16[8192][256] hi   (4MB)
#define F_EMBT    9437184ull    // fp32 embedT[256][8192] (8MB, rescore)
#define F_E2N     11534336ull   // 8192  (-0.5*e2, fast path)
#define F_E2NP    11542528ull   // 8192  (numpy-emulated e2)
#define F_IDS     11550720ull   // 32768 ints
#define F_FLAGCNT 11583488ull
#define F_LOSS    11583489ull
#define F_FLAGLST 11583490ull   // up to 32768 ints
#define F_COUNTS  11616258ull   // 8192 ints
#define F_CURSOR  11624450ull   // 8192 ints
#define F_OFFS    11632642ull   // 8192 ints
#define F_BUCKET  11640834ull   // 32768 ints
#define F_PBD     11673602ull   // 2048*8 floats
#define F_PBI     11689986ull   // 2048*8 ints

// ---- output float offsets ----
#define OUT_ST   0ull
#define OUT_LOSS 8388608ull
#define OUT_IDS  8388609ull
#define OUT_NEMB 8421377ull
#define OUT_NUM  10518529ull
#define OUT_ENC  10526721ull

// numpy pairwise_sum for a 128-block: 8 accumulators, fixed combine tree.
__device__ __forceinline__ float np_pw128(const float* p) {
    float r0 = p[0], r1 = p[1], r2 = p[2], r3 = p[3];
    float r4 = p[4], r5 = p[5], r6 = p[6], r7 = p[7];
    for (int i = 8; i < 128; i += 8) {
        r0 += p[i + 0]; r1 += p[i + 1]; r2 += p[i + 2]; r3 += p[i + 3];
        r4 += p[i + 4]; r5 += p[i + 5]; r6 += p[i + 6]; r7 += p[i + 7];
    }
    return ((r0 + r1) + (r2 + r3)) + ((r4 + r5) + (r6 + r7));
}

// x (b,c,h,w) -> xh/xl[n][c] f16 split, n = b*1024 + w*32 + h
__global__ void k_cvt_x(const float* __restrict__ x,
                        _Float16* __restrict__ xh, _Float16* __restrict__ xl) {
    __shared__ float t[32 * 529];   // [c32][h16*33 + w]
    const int bx = blockIdx.x;
    const int b = bx >> 4, cg = (bx >> 1) & 7, h0 = (bx & 1) * 16;
    const int tid = threadIdx.x;
    const float* src = x + ((size_t)(b * 256 + cg * 32)) * 1024 + h0 * 32;
    for (int i = 0; i < 64; ++i) {
        int e = i * 256 + tid;
        int c = e >> 9, rem = e & 511;
        int hh = rem >> 5, w = rem & 31;
        t[c * 529 + hh * 33 + w] = src[(size_t)c * 1024 + hh * 32 + w];
    }
    __syncthreads();
    const int ni = tid >> 5, c = tid & 31;
    for (int i = 0; i < 64; ++i) {
        int ns = i * 8 + ni;             // 0..511 = w*16 + hh
        int w = ns >> 4, hh = ns & 15;
        float v = t[c * 529 + hh * 33 + w];
        _Float16 hi = (_Float16)v;
        _Float16 lo = (_Float16)(v - (float)hi);
        size_t o = ((size_t)(b * 1024 + w * 32 + h0 + hh)) * 256 + cg * 32 + c;
        xh[o] = hi; xl[o] = lo;
    }
}

// embed -> eh f16 (hi only) + e2n = -0.5*|e|^2
__global__ void k_prep_e(const float* __restrict__ embed,
                         _Float16* __restrict__ eh, float* __restrict__ e2n) {
    int wave = threadIdx.x >> 6, lane = threadIdx.x & 63;
    int k = blockIdx.x * 4 + wave;
    float4 v = *(const float4*)(embed + (size_t)k * CD + lane * 4);
    f16x4 h;
    h[0] = (_Float16)v.x; h[1] = (_Float16)v.y;
    h[2] = (_Float16)v.z; h[3] = (_Float16)v.w;
    *(f16x4*)&eh[(size_t)k * CD + lane * 4] = h;
    float s = v.x * v.x + v.y * v.y + v.z * v.z + v.w * v.w;
    #pragma unroll
    for (int off = 1; off < 64; off <<= 1) s += __shfl_xor(s, off);
    if (lane == 0) e2n[k] = -0.5f * s;
}

// numpy-emulated e2, wave-parallel: 8 lanes per k, exact pairwise tree.
__global__ void k_e2np(const float* __restrict__ embed, float* __restrict__ e2np) {
    const int lane = threadIdx.x & 63;
    const int wv = threadIdx.x >> 6;
    const int k = blockIdx.x * 32 + wv * 8 + (lane >> 3);
    const int j = lane & 7;
    float hsum[2];
    #pragma unroll
    for (int half = 0; half < 2; ++half) {
        float r = 0.f;
        for (int i = 0; i < 16; ++i) {
            float v = embed[(size_t)k * CD + half * 128 + j + i * 8];
            float sq = v * v;
            asm volatile("" : "+v"(sq));   // round v*v to fp32 (block contraction)
            r += sq;
        }
        float s = r + __shfl_xor(r, 1);
        s = s + __shfl_xor(s, 2);
        s = s + __shfl_xor(s, 4);
        hsum[half] = s;
    }
    if (j == 0) e2np[k] = hsum[0] + hsum[1];
}

// embed (k,c) -> embedT[c][k] fp32 (rescore only)
__global__ void k_epose(const float* __restrict__ embed, float* __restrict__ embedT) {
    int kt = blockIdx.x >> 2, ct = blockIdx.x & 3;
    __shared__ float t[64][65];
    int tid = threadIdx.x;
    #pragma unroll
    for (int i = 0; i < 16; ++i) {
        int e = tid + i * 256; int r = e >> 6, c = e & 63;
        t[r][c] = embed[(size_t)(kt * 64 + r) * CD + ct * 64 + c];
    }
    __syncthreads();
    #pragma unroll
    for (int i = 0; i < 16; ++i) {
        int e = tid + i * 256; int c = e >> 6, r = e & 63;
        embedT[(size_t)(ct * 64 + c) * KD + kt * 64 + r] = t[r][c];
    }
}

// ============================================================================
// Operand-swapped MFMA argmin: D[code][row] = eh x xh^T.
// Block: 128 rows (xh resident in LDS, 64KB), kt-loop 16 x 512-code chunks
// (eh streamed 32KB/step, double-buffered). 8 waves = 4 (code) x 2 (row).
// Wave tile: 128 codes x 64 rows -> acc[8][4] f32x4. Top-2 per pixel-row
// accumulates IN REGISTERS across all 8192 codes; cross-lane merge once.
// -0.5*e2 pre-folded into MFMA C-init. Ties auto-flag (m2==m1).
// ============================================================================
#define LDSB 0
#define LDSA 65536
#define LDSM 131072
__global__ __launch_bounds__(512, 2) void k_mfma(
    const _Float16* __restrict__ xh, const _Float16* __restrict__ eh,
    const float* __restrict__ e2n, int* __restrict__ ids,
    int* __restrict__ flag_cnt, int* __restrict__ flag_list,
    int* __restrict__ counts)
{
    __shared__ char smem[65536 + 65536 + 6144];
    const int tid = threadIdx.x;
    const int w = tid >> 6, l = tid & 63;
    const int wm = w & 3, wn = w >> 2;        // 4 code-waves x 2 row-waves
    const int lr = l & 15, q = l >> 4;
    const int n0 = blockIdx.x * 128;

    // ---- stage B (xh rows) resident, swizzled slot' = slot ^ (row&15) ----
    #pragma unroll
    for (int i = 0; i < 8; ++i) {
        const int row = i * 16 + (tid >> 5);
        const int slot = tid & 31;
        const _Float16* src = xh + (size_t)(n0 + row) * 256 + ((slot ^ (row & 15)) * 8);
        __builtin_amdgcn_global_load_lds(
            (const __attribute__((address_space(1))) unsigned int*)src,
            (__attribute__((address_space(3))) unsigned int*)(smem + LDSB + row * 512 + slot * 16),
            16, 0, 0);
    }

    // ---- A stage helper: 512 codes x 32 c chunk, swizzle slot' = slot ^ ((code>>1)&3)
    auto STAGE_A = [&](int buf, int step) {
        const int kt = step >> 3, c0 = (step & 7) * 32;
        #pragma unroll
        for (int i = 0; i < 4; ++i) {
            const int code = i * 128 + (tid >> 2);
            const int slot = tid & 3;
            const _Float16* src = eh + (size_t)(kt * 512 + code) * 256 + c0
                                     + ((slot ^ ((code >> 1) & 3)) * 8);
            __builtin_amdgcn_global_load_lds(
                (const __attribute__((address_space(1))) unsigned int*)src,
                (__attribute__((address_space(3))) unsigned int*)
                    (smem + LDSA + buf * 32768 + code * 64 + slot * 16),
                16, 0, 0);
        }
    };

    STAGE_A(0, 0);
    __syncthreads();

    f32x4 acc[8][4];
    float e2v[8][4];
    // init acc for kt=0: acc = -0.5*e2 (per code, broadcast over rows)
    #pragma unroll
    for (int m = 0; m < 8; ++m) {
        const f32x4 ev = *(const f32x4*)(e2n + wm * 128 + m * 16 + q * 4);
        #pragma unroll
        for (int r = 0; r < 4; ++r) e2v[m][r] = ev[r];
    }
    #pragma unroll
    for (int m = 0; m < 8; ++m)
        #pragma unroll
        for (int n = 0; n < 4; ++n)
            #pragma unroll
            for (int r = 0; r < 4; ++r) acc[m][n][r] = e2v[m][r];

    float m1[4], m2[4]; int i1[4];
    #pragma unroll
    for (int n = 0; n < 4; ++n) { m1[n] = -3.4e38f; m2[n] = -3.4e38f; i1[n] = 0; }

    // precomputed fa LDS byte offsets (constant per lane; only buf alternates)
    int faoff[8];
    #pragma unroll
    for (int m = 0; m < 8; ++m) {
        const int code = wm * 128 + m * 16 + lr;
        faoff[m] = LDSA + code * 64 + ((q ^ ((code >> 1) & 3)) * 16);
    }
    int fboff[4];   // base (slot g=q part folded per-step below)
    #pragma unroll
    for (int n = 0; n < 4; ++n) fboff[n] = (wn * 64 + n * 16 + lr) * 512;
    const int rowx15[4] = { (wn * 64 + 0 * 16 + lr) & 15, (wn * 64 + 1 * 16 + lr) & 15,
                            (wn * 64 + 2 * 16 + lr) & 15, (wn * 64 + 3 * 16 + lr) & 15 };

    int buf = 0;
    #pragma unroll 1
    for (int kt = 0; kt < 16; ++kt) {
        #pragma unroll
        for (int sin = 0; sin < 8; ++sin) {
            const int step = kt * 8 + sin;
            if (step < 127) STAGE_A(buf ^ 1, step + 1);
            f16x8 fa[8], fb[4];
            #pragma unroll
            for (int m = 0; m < 8; ++m)
                fa[m] = *(const f16x8*)(smem + buf * 32768 + faoff[m]);
            #pragma unroll
            for (int n = 0; n < 4; ++n) {
                const int g = sin * 4 + q;
                fb[n] = *(const f16x8*)(smem + LDSB + fboff[n] + ((g ^ rowx15[n]) * 16));
            }
            #pragma unroll
            for (int m = 0; m < 8; ++m)
                #pragma unroll
                for (int n = 0; n < 4; ++n)
                    acc[m][n] = __builtin_amdgcn_mfma_f32_16x16x32_f16(fa[m], fb[n], acc[m][n], 0, 0, 0);
            __syncthreads();
            buf ^= 1;
        }
        // ---- end of kt: fold acc into per-lane top-2, then re-init ----
        const int kb = kt * 512 + wm * 128 + q * 4;
        #pragma unroll
        for (int n = 0; n < 4; ++n) {
            #pragma unroll
            for (int m = 0; m < 8; ++m) {
                #pragma unroll
                for (int r = 0; r < 4; ++r) {
                    const float v = acc[m][n][r];
                    const bool g = v > m1[n];
                    m2[n] = fmaxf(m2[n], fminf(v, m1[n]));
                    m1[n] = fmaxf(m1[n], v);
                    i1[n] = g ? (kb + m * 16 + r) : i1[n];
                }
            }
        }
        if (kt < 15) {
            #pragma unroll
            for (int m = 0; m < 8; ++m) {
                const f32x4 ev = *(const f32x4*)(e2n + (kt + 1) * 512 + wm * 128 + m * 16 + q * 4);
                #pragma unroll
                for (int r = 0; r < 4; ++r) e2v[m][r] = ev[r];
            }
            #pragma unroll
            for (int m = 0; m < 8; ++m)
                #pragma unroll
                for (int n = 0; n < 4; ++n)
                    #pragma unroll
                    for (int r = 0; r < 4; ++r) acc[m][n][r] = e2v[m][r];
        }
    }

    // ---- cross-lane merge: lanes l, l+16, l+32, l+48 hold same row, diff codes
    #pragma unroll
    for (int off = 16; off < 64; off <<= 1) {
        #pragma unroll
        for (int n = 0; n < 4; ++n) {
            const float om1 = __shfl_xor(m1[n], off);
            const float om2 = __shfl_xor(m2[n], off);
            const int   oi  = __shfl_xor(i1[n], off);
            const bool g = om1 > m1[n];
            m2[n] = fmaxf(fminf(m1[n], om1), fmaxf(m2[n], om2));
            m1[n] = fmaxf(m1[n], om1);
            i1[n] = g ? oi : i1[n];
        }
    }
    // ---- cross-wave merge over wm (4 code-wave groups) via LDS ----
    float* sm1 = (float*)(smem + LDSM);
    float* sm2 = (float*)(smem + LDSM + 2048);
    int*   si1 = (int*)  (smem + LDSM + 4096);
    __syncthreads();
    if (q == 0) {
        #pragma unroll
        for (int n = 0; n < 4; ++n) {
            const int row = wn * 64 + n * 16 + lr;
            sm1[wm * 128 + row] = m1[n];
            sm2[wm * 128 + row] = m2[n];
            si1[wm * 128 + row] = i1[n];
        }
    }
    __syncthreads();
    if (tid < 128) {
        float a1 = sm1[tid], a2 = sm2[tid]; int ai = si1[tid];
        #pragma unroll
        for (int wq = 1; wq < 4; ++wq) {
            const float b1 = sm1[wq * 128 + tid], b2 = sm2[wq * 128 + tid];
            const int bi = si1[wq * 128 + tid];
            const bool g = b1 > a1;
            a2 = fmaxf(fminf(a1, b1), fmaxf(a2, b2));
            a1 = fmaxf(a1, b1);
            ai = g ? bi : ai;
        }
        const int n = n0 + tid;
        ids[n] = ai;
        atomicAdd(&counts[ai], 1);
        if (a1 - a2 < 2.5e-3f) {
            int p = atomicAdd(flag_cnt, 1);
            flag_list[p] = n;
        }
    }
}

// batched numpy-fp32-path rescore: 16 rows/group x 8 k-slices per block.
#define RG 16
__global__ __launch_bounds__(256) void k_rescore(
    const float* __restrict__ x, const float* __restrict__ embedT,
    const float* __restrict__ e2np, const int* __restrict__ flag_cnt,
    const int* __restrict__ flag_list, float* __restrict__ pbd, int* __restrict__ pbi)
{
    __shared__ float rowl[RG][256];
    __shared__ float sq[RG][256];
    __shared__ float x2s[RG];
    __shared__ float bdA[256];
    __shared__ int   biA[256];
    const int tid = threadIdx.x;
    int cnt = *flag_cnt; if (cnt > 2048) cnt = 2048;
    const int ngroups = (cnt + RG - 1) / RG;
    const int kt = blockIdx.x & 7;
    for (int g = blockIdx.x >> 3; g < ngroups; g += 64) {
        #pragma unroll
        for (int i = 0; i < RG; ++i) {
            int f = g * RG + i;
            float v = 0.f;
            if (f < cnt) {
                int n = flag_list[f];
                int b = n >> 10, wq = (n >> 5) & 31, hq = n & 31;
                v = x[((size_t)(b * 256 + tid)) * 1024 + hq * 32 + wq];
            }
            rowl[i][tid] = v;
            sq[i][tid] = v * v;       // product rounds at LDS store
        }
        __syncthreads();
        if (tid < RG) x2s[tid] = np_pw128(sq[tid]) + np_pw128(sq[tid] + 128);
        __syncthreads();

        float acc[RG][4];
        #pragma unroll
        for (int r = 0; r < RG; ++r)
            #pragma unroll
            for (int e = 0; e < 4; ++e) acc[r][e] = 0.f;
        for (int c = 0; c < 256; ++c) {
            const f32x4 bv = *(const f32x4*)&embedT[(size_t)c * KD + kt * 1024 + tid * 4];
            #pragma unroll
            for (int r = 0; r < RG; ++r) {
                const float av = rowl[r][c];
                acc[r][0] = fmaf(av, bv[0], acc[r][0]);
                acc[r][1] = fmaf(av, bv[1], acc[r][1]);
                acc[r][2] = fmaf(av, bv[2], acc[r][2]);
                acc[r][3] = fmaf(av, bv[3], acc[r][3]);
            }
        }
        #pragma unroll
        for (int r = 0; r < RG; ++r) {
            float bd = 3.4e38f; int bi = 0x7fffffff;
            #pragma unroll
            for (int e = 0; e < 4; ++e) {
                const int k = kt * 1024 + tid * 4 + e;
                const float d2 = (x2s[r] - 2.0f * acc[r][e]) + e2np[k];
                if (d2 < bd || (d2 == bd && k < bi)) { bd = d2; bi = k; }
            }
            bdA[tid] = bd; biA[tid] = bi;
            __syncthreads();
            for (int off = 128; off > 0; off >>= 1) {
                if (tid < off) {
                    float od = bdA[tid + off]; int oi = biA[tid + off];
                    if (od < bdA[tid] || (od == bdA[tid] && oi < biA[tid])) {
                        bdA[tid] = od; biA[tid] = oi;
                    }
                }
                __syncthreads();
            }
            if (tid == 0) {
                int f = g * RG + r;
                if (f < cnt) { pbd[f * 8 + kt] = bdA[0]; pbi[f * 8 + kt] = biA[0]; }
            }
            __syncthreads();
        }
    }
}

// merge kt-slices; adjust ids + counts for changed rows
__global__ void k_flagmerge(const int* __restrict__ flag_cnt, const int* __restrict__ flag_list,
                            const float* __restrict__ pbd, const int* __restrict__ pbi,
                            int* __restrict__ ids, int* __restrict__ counts) {
    int cnt = *flag_cnt; if (cnt > 2048) cnt = 2048;
    int f = blockIdx.x * 256 + threadIdx.x;
    if (f >= cnt) return;
    float bd = pbd[f * 8]; int bi = pbi[f * 8];
    #pragma unroll
    for (int kt = 1; kt < 8; ++kt) {
        float d = pbd[f * 8 + kt]; int i = pbi[f * 8 + kt];
        if (d < bd || (d == bd && i < bi)) { bd = d; bi = i; }
    }
    const int n = flag_list[f];
    const int old = ids[n];
    if (bi != old) {
        ids[n] = bi;
        atomicAdd(&counts[old], -1);
        atomicAdd(&counts[bi], 1);
    }
}

// st_out (= vqs) + loss partial sums
__global__ void k_output(const float* __restrict__ x, const float* __restrict__ embed,
                         const int* __restrict__ ids, float* __restrict__ st,
                         float* __restrict__ loss_ws)
{
    const size_t base = ((size_t)blockIdx.x * 256 + threadIdx.x) * 4;
    const int w = (int)(base & 31);
    const int h = (int)((base >> 5) & 31);
    const int c = (int)((base >> 10) & 255);
    const int b = (int)(base >> 18);
    const float4 xv = *(const float4*)(x + base);
    const int nb = b * 1024 + h;
    const float vq0 = embed[(size_t)ids[nb + (w + 0) * 32] * CD + c];
    const float vq1 = embed[(size_t)ids[nb + (w + 1) * 32] * CD + c];
    const float vq2 = embed[(size_t)ids[nb + (w + 2) * 32] * CD + c];
    const float vq3 = embed[(size_t)ids[nb + (w + 3) * 32] * CD + c];
    *(float4*)(st + base) = make_float4(vq0, vq1, vq2, vq3);
    const float d0 = vq0 - xv.x, d1 = vq1 - xv.y, d2 = vq2 - xv.z, d3 = vq3 - xv.w;
    float s = d0 * d0 + d1 * d1 + d2 * d2 + d3 * d3;
    #pragma unroll
    for (int off = 1; off < 64; off <<= 1) s += __shfl_xor(s, off);
    if ((threadIdx.x & 63) == 0) atomicAdd(loss_ws, s);
}

__global__ void k_ids(const int* __restrict__ ids, float* __restrict__ ids_out) {
    int e = blockIdx.x * 256 + threadIdx.x;
    int b = e >> 10, h = (e >> 5) & 31, w = e & 31;
    ids_out[e] = (float)ids[b * 1024 + w * 32 + h];
}

__global__ void k_scan(const int* __restrict__ counts, int* __restrict__ offs,
                       float* __restrict__ track_num) {
    __shared__ int ps[257];
    const int tid = threadIdx.x;
    int loc[32]; int s = 0;
    const int base = tid * 32;
    #pragma unroll
    for (int j = 0; j < 32; ++j) { loc[j] = s; s += counts[base + j]; }
    ps[tid + 1] = s;
    if (tid == 0) ps[0] = 0;
    __syncthreads();
    if (tid == 0) for (int i = 1; i <= 256; ++i) ps[i] += ps[i - 1];
    __syncthreads();
    const int pre = ps[tid];
    #pragma unroll
    for (int j = 0; j < 32; ++j) {
        offs[base + j] = pre + loc[j];
        track_num[base + j] = (float)counts[base + j];
    }
}

__global__ void k_fill(const int* __restrict__ ids, const int* __restrict__ offs,
                       int* __restrict__ cursor, int* __restrict__ bucket) {
    int n = blockIdx.x * 256 + threadIdx.x;
    int id = ids[n];
    int p = atomicAdd(&cursor[id], 1);
    bucket[offs[id] + p] = n;
}

// track_enc[k][c] = sum over bucket rows of (xh + xl)  (no atomics)
__global__ void k_gather(const _Float16* __restrict__ xh, const _Float16* __restrict__ xl,
                         const int* __restrict__ offs, const int* __restrict__ counts,
                         const int* __restrict__ bucket, float* __restrict__ enc) {
    const int k = blockIdx.x, c = threadIdx.x;
    const int o = offs[k], cnt = counts[k];
    float s = 0.f;
    for (int i = 0; i < cnt; ++i) {
        int n = bucket[o + i];
        s += (float)xh[(size_t)n * CD + c] + (float)xl[(size_t)n * CD + c];
    }
    enc[(size_t)k * CD + c] = s;
}

__global__ void k_final(const float* __restrict__ track_num, const float* __restrict__ track_enc,
                        float* __restrict__ new_embed, const float* __restrict__ loss_ws,
                        float* __restrict__ loss_out)
{
    const size_t e = (size_t)blockIdx.x * 256 + threadIdx.x;
    const int k = (int)(e >> 8);
    const float factor = 1.0f + (1e-5f * 8192.0f) / 32768.0f;
    new_embed[e] = track_enc[e] * factor / (track_num[k] + 1e-5f);
    if (e == 0) loss_out[0] = loss_ws[0] * (1.0f / 8388608.0f);
}

extern "C" void kernel_launch(void* const* d_in, const int* in_sizes, int n_in,
                              void* d_out, int out_size, void* d_ws, size_t ws_size,
                              hipStream_t stream)
{
    const float* x     = (const float*)d_in[0];
    const float* embed = (const float*)d_in[1];
    float* out = (float*)d_out;
    float* ws  = (float*)d_ws;

    _Float16* xh = (_Float16*)(ws + F_XH);
    _Float16* xl = (_Float16*)(ws + F_XL);
    _Float16* eh = (_Float16*)(ws + F_EH);
    float* embedT    = ws + F_EMBT;
    float* e2n       = ws + F_E2N;
    float* e2np      = ws + F_E2NP;
    int*   ids       = (int*)(ws + F_IDS);
    int*   flag_cnt  = (int*)(ws + F_FLAGCNT);
    float* loss_ws   = ws + F_LOSS;
    int*   flag_list = (int*)(ws + F_FLAGLST);
    int*   counts    = (int*)(ws + F_COUNTS);
    int*   cursor    = (int*)(ws + F_CURSOR);
    int*   offs      = (int*)(ws + F_OFFS);
    int*   bucket    = (int*)(ws + F_BUCKET);
    float* pbd       = ws + F_PBD;
    int*   pbi       = (int*)(ws + F_PBI);

    hipMemsetAsync(ws + F_FLAGCNT, 0, 2 * sizeof(float), stream);          // flag_cnt + loss
    hipMemsetAsync(ws + F_COUNTS, 0, 2 * 8192 * sizeof(float), stream);    // counts + cursor

    k_cvt_x    <<<512,  256, 0, stream>>>(x, xh, xl);
    k_prep_e   <<<2048, 256, 0, stream>>>(embed, eh, e2n);
    k_e2np     <<<256,  256, 0, stream>>>(embed, e2np);
    k_epose    <<<512,  256, 0, stream>>>(embed, embedT);
    k_mfma     <<<256,  512, 0, stream>>>(xh, eh, e2n, ids, flag_cnt, flag_list, counts);
    k_rescore  <<<512,  256, 0, stream>>>(x, embedT, e2np, flag_cnt, flag_list, pbd, pbi);
    k_flagmerge<<<8,    256, 0, stream>>>(flag_cnt, flag_list, pbd, pbi, ids, counts);
    k_output   <<<8192, 256, 0, stream>>>(x, embed, ids, out + OUT_ST, loss_ws);
    k_ids      <<<128,  256, 0, stream>>>(ids, out + OUT_IDS);
    k_scan     <<<1,    256, 0, stream>>>(counts, offs, out + OUT_NUM);
    k_fill     <<<128,  256, 0, stream>>>(ids, offs, cursor, bucket);
    k_gather   <<<8192, 256, 0, stream>>>(xh, xl, offs, counts, bucket, out + OUT_ENC);
    k_final    <<<8192, 256, 0, stream>>>(out + OUT_NUM, out + OUT_ENC, out + OUT_NEMB,
                                          loss_ws, out + OUT_LOSS);
}

// Round 6
// 461.013 us; speedup vs baseline: 10.5610x; 1.7854x over previous
//
#include <hip/hip_runtime.h>

#define NR 32768   // rows (b*w*h)
#define CD 256     // emb dim
#define KD 8192    // dict size

typedef __attribute__((ext_vector_type(8))) _Float16 f16x8;
typedef __attribute__((ext_vector_type(4))) _Float16 f16x4;
typedef __attribute__((ext_vector_type(4))) float f32x4;

// ---- workspace float offsets ----
#define F_XH      0ull          // f16[32768][256] hi  (16MB)
#define F_XL      4194304ull    // f16[32768][256] lo  (16MB)
#define F_EH      8388608ull    // f16[8192][256] hi   (4MB)
#define F_EMBT    9437184ull    // fp32 embedT[256][8192] (8MB, rescore)
#define F_E2N     11534336ull   // 8192  (-0.5*e2, fast path)
#define F_E2NP    11542528ull   // 8192  (numpy-emulated e2)
#define F_IDS     11550720ull   // 32768 ints
#define F_FLAGCNT 11583488ull
#define F_LOSS    11583489ull
#define F_FLAGLST 11583490ull   // up to 32768 ints
#define F_COUNTS  11616258ull   // 8192 ints
#define F_CURSOR  11624450ull   // 8192 ints
#define F_OFFS    11632642ull   // 8192 ints
#define F_BUCKET  11640834ull   // 32768 ints
#define F_PBD     11673602ull   // 2048*8 floats
#define F_PBI     11689986ull   // 2048*8 ints

// ---- output float offsets ----
#define OUT_ST   0ull
#define OUT_LOSS 8388608ull
#define OUT_IDS  8388609ull
#define OUT_NEMB 8421377ull
#define OUT_NUM  10518529ull
#define OUT_ENC  10526721ull

// numpy pairwise_sum for a 128-block: 8 accumulators, fixed combine tree.
__device__ __forceinline__ float np_pw128(const float* p) {
    float r0 = p[0], r1 = p[1], r2 = p[2], r3 = p[3];
    float r4 = p[4], r5 = p[5], r6 = p[6], r7 = p[7];
    for (int i = 8; i < 128; i += 8) {
        r0 += p[i + 0]; r1 += p[i + 1]; r2 += p[i + 2]; r3 += p[i + 3];
        r4 += p[i + 4]; r5 += p[i + 5]; r6 += p[i + 6]; r7 += p[i + 7];
    }
    return ((r0 + r1) + (r2 + r3)) + ((r4 + r5) + (r6 + r7));
}

// x (b,c,h,w) -> xh/xl[n][c] f16 split, n = b*1024 + w*32 + h
__global__ void k_cvt_x(const float* __restrict__ x,
                        _Float16* __restrict__ xh, _Float16* __restrict__ xl) {
    __shared__ float t[32 * 529];   // [c32][h16*33 + w]
    const int bx = blockIdx.x;
    const int b = bx >> 4, cg = (bx >> 1) & 7, h0 = (bx & 1) * 16;
    const int tid = threadIdx.x;
    const float* src = x + ((size_t)(b * 256 + cg * 32)) * 1024 + h0 * 32;
    for (int i = 0; i < 64; ++i) {
        int e = i * 256 + tid;
        int c = e >> 9, rem = e & 511;
        int hh = rem >> 5, w = rem & 31;
        t[c * 529 + hh * 33 + w] = src[(size_t)c * 1024 + hh * 32 + w];
    }
    __syncthreads();
    const int ni = tid >> 5, c = tid & 31;
    for (int i = 0; i < 64; ++i) {
        int ns = i * 8 + ni;             // 0..511 = w*16 + hh
        int w = ns >> 4, hh = ns & 15;
        float v = t[c * 529 + hh * 33 + w];
        _Float16 hi = (_Float16)v;
        _Float16 lo = (_Float16)(v - (float)hi);
        size_t o = ((size_t)(b * 1024 + w * 32 + h0 + hh)) * 256 + cg * 32 + c;
        xh[o] = hi; xl[o] = lo;
    }
}

// embed -> eh f16 (hi only) + e2n = -0.5*|e|^2
__global__ void k_prep_e(const float* __restrict__ embed,
                         _Float16* __restrict__ eh, float* __restrict__ e2n) {
    int wave = threadIdx.x >> 6, lane = threadIdx.x & 63;
    int k = blockIdx.x * 4 + wave;
    float4 v = *(const float4*)(embed + (size_t)k * CD + lane * 4);
    f16x4 h;
    h[0] = (_Float16)v.x; h[1] = (_Float16)v.y;
    h[2] = (_Float16)v.z; h[3] = (_Float16)v.w;
    *(f16x4*)&eh[(size_t)k * CD + lane * 4] = h;
    float s = v.x * v.x + v.y * v.y + v.z * v.z + v.w * v.w;
    #pragma unroll
    for (int off = 1; off < 64; off <<= 1) s += __shfl_xor(s, off);
    if (lane == 0) e2n[k] = -0.5f * s;
}

// numpy-emulated e2, wave-parallel: 8 lanes per k, exact pairwise tree.
__global__ void k_e2np(const float* __restrict__ embed, float* __restrict__ e2np) {
    const int lane = threadIdx.x & 63;
    const int wv = threadIdx.x >> 6;
    const int k = blockIdx.x * 32 + wv * 8 + (lane >> 3);
    const int j = lane & 7;
    float hsum[2];
    #pragma unroll
    for (int half = 0; half < 2; ++half) {
        float r = 0.f;
        for (int i = 0; i < 16; ++i) {
            float v = embed[(size_t)k * CD + half * 128 + j + i * 8];
            float sq = v * v;
            asm volatile("" : "+v"(sq));   // round v*v to fp32 (block contraction)
            r += sq;
        }
        float s = r + __shfl_xor(r, 1);
        s = s + __shfl_xor(s, 2);
        s = s + __shfl_xor(s, 4);
        hsum[half] = s;
    }
    if (j == 0) e2np[k] = hsum[0] + hsum[1];
}

// embed (k,c) -> embedT[c][k] fp32 (rescore only)
__global__ void k_epose(const float* __restrict__ embed, float* __restrict__ embedT) {
    int kt = blockIdx.x >> 2, ct = blockIdx.x & 3;
    __shared__ float t[64][65];
    int tid = threadIdx.x;
    #pragma unroll
    for (int i = 0; i < 16; ++i) {
        int e = tid + i * 256; int r = e >> 6, c = e & 63;
        t[r][c] = embed[(size_t)(kt * 64 + r) * CD + ct * 64 + c];
    }
    __syncthreads();
    #pragma unroll
    for (int i = 0; i < 16; ++i) {
        int e = tid + i * 256; int c = e >> 6, r = e & 63;
        embedT[(size_t)(ct * 64 + c) * KD + kt * 64 + r] = t[r][c];
    }
}

// ============================================================================
// Operand-swapped MFMA argmin: D[code][row] = eh x xh^T.  (validated round 5)
// ============================================================================
#define LDSB 0
#define LDSA 65536
#define LDSM 131072
__global__ __launch_bounds__(512, 2) void k_mfma(
    const _Float16* __restrict__ xh, const _Float16* __restrict__ eh,
    const float* __restrict__ e2n, int* __restrict__ ids,
    int* __restrict__ flag_cnt, int* __restrict__ flag_list,
    int* __restrict__ counts)
{
    __shared__ char smem[65536 + 65536 + 6144];
    const int tid = threadIdx.x;
    const int w = tid >> 6, l = tid & 63;
    const int wm = w & 3, wn = w >> 2;        // 4 code-waves x 2 row-waves
    const int lr = l & 15, q = l >> 4;
    const int n0 = blockIdx.x * 128;

    // ---- stage B (xh rows) resident, swizzled slot' = slot ^ (row&15) ----
    #pragma unroll
    for (int i = 0; i < 8; ++i) {
        const int row = i * 16 + (tid >> 5);
        const int slot = tid & 31;
        const _Float16* src = xh + (size_t)(n0 + row) * 256 + ((slot ^ (row & 15)) * 8);
        __builtin_amdgcn_global_load_lds(
            (const __attribute__((address_space(1))) unsigned int*)src,
            (__attribute__((address_space(3))) unsigned int*)(smem + LDSB + row * 512 + slot * 16),
            16, 0, 0);
    }

    // ---- A stage helper: 512 codes x 32 c chunk, swizzle slot' = slot ^ ((code>>1)&3)
    auto STAGE_A = [&](int buf, int step) {
        const int kt = step >> 3, c0 = (step & 7) * 32;
        #pragma unroll
        for (int i = 0; i < 4; ++i) {
            const int code = i * 128 + (tid >> 2);
            const int slot = tid & 3;
            const _Float16* src = eh + (size_t)(kt * 512 + code) * 256 + c0
                                     + ((slot ^ ((code >> 1) & 3)) * 8);
            __builtin_amdgcn_global_load_lds(
                (const __attribute__((address_space(1))) unsigned int*)src,
                (__attribute__((address_space(3))) unsigned int*)
                    (smem + LDSA + buf * 32768 + code * 64 + slot * 16),
                16, 0, 0);
        }
    };

    STAGE_A(0, 0);
    __syncthreads();

    f32x4 acc[8][4];
    float e2v[8][4];
    #pragma unroll
    for (int m = 0; m < 8; ++m) {
        const f32x4 ev = *(const f32x4*)(e2n + wm * 128 + m * 16 + q * 4);
        #pragma unroll
        for (int r = 0; r < 4; ++r) e2v[m][r] = ev[r];
    }
    #pragma unroll
    for (int m = 0; m < 8; ++m)
        #pragma unroll
        for (int n = 0; n < 4; ++n)
            #pragma unroll
            for (int r = 0; r < 4; ++r) acc[m][n][r] = e2v[m][r];

    float m1[4], m2[4]; int i1[4];
    #pragma unroll
    for (int n = 0; n < 4; ++n) { m1[n] = -3.4e38f; m2[n] = -3.4e38f; i1[n] = 0; }

    int faoff[8];
    #pragma unroll
    for (int m = 0; m < 8; ++m) {
        const int code = wm * 128 + m * 16 + lr;
        faoff[m] = LDSA + code * 64 + ((q ^ ((code >> 1) & 3)) * 16);
    }
    int fboff[4];
    #pragma unroll
    for (int n = 0; n < 4; ++n) fboff[n] = (wn * 64 + n * 16 + lr) * 512;
    const int rowx15[4] = { (wn * 64 + 0 * 16 + lr) & 15, (wn * 64 + 1 * 16 + lr) & 15,
                            (wn * 64 + 2 * 16 + lr) & 15, (wn * 64 + 3 * 16 + lr) & 15 };

    int buf = 0;
    #pragma unroll 1
    for (int kt = 0; kt < 16; ++kt) {
        #pragma unroll
        for (int sin = 0; sin < 8; ++sin) {
            const int step = kt * 8 + sin;
            if (step < 127) STAGE_A(buf ^ 1, step + 1);
            f16x8 fa[8], fb[4];
            #pragma unroll
            for (int m = 0; m < 8; ++m)
                fa[m] = *(const f16x8*)(smem + buf * 32768 + faoff[m]);
            #pragma unroll
            for (int n = 0; n < 4; ++n) {
                const int g = sin * 4 + q;
                fb[n] = *(const f16x8*)(smem + LDSB + fboff[n] + ((g ^ rowx15[n]) * 16));
            }
            #pragma unroll
            for (int m = 0; m < 8; ++m)
                #pragma unroll
                for (int n = 0; n < 4; ++n)
                    acc[m][n] = __builtin_amdgcn_mfma_f32_16x16x32_f16(fa[m], fb[n], acc[m][n], 0, 0, 0);
            __syncthreads();
            buf ^= 1;
        }
        const int kb = kt * 512 + wm * 128 + q * 4;
        #pragma unroll
        for (int n = 0; n < 4; ++n) {
            #pragma unroll
            for (int m = 0; m < 8; ++m) {
                #pragma unroll
                for (int r = 0; r < 4; ++r) {
                    const float v = acc[m][n][r];
                    const bool g = v > m1[n];
                    m2[n] = fmaxf(m2[n], fminf(v, m1[n]));
                    m1[n] = fmaxf(m1[n], v);
                    i1[n] = g ? (kb + m * 16 + r) : i1[n];
                }
            }
        }
        if (kt < 15) {
            #pragma unroll
            for (int m = 0; m < 8; ++m) {
                const f32x4 ev = *(const f32x4*)(e2n + (kt + 1) * 512 + wm * 128 + m * 16 + q * 4);
                #pragma unroll
                for (int r = 0; r < 4; ++r) e2v[m][r] = ev[r];
            }
            #pragma unroll
            for (int m = 0; m < 8; ++m)
                #pragma unroll
                for (int n = 0; n < 4; ++n)
                    #pragma unroll
                    for (int r = 0; r < 4; ++r) acc[m][n][r] = e2v[m][r];
        }
    }

    #pragma unroll
    for (int off = 16; off < 64; off <<= 1) {
        #pragma unroll
        for (int n = 0; n < 4; ++n) {
            const float om1 = __shfl_xor(m1[n], off);
            const float om2 = __shfl_xor(m2[n], off);
            const int   oi  = __shfl_xor(i1[n], off);
            const bool g = om1 > m1[n];
            m2[n] = fmaxf(fminf(m1[n], om1), fmaxf(m2[n], om2));
            m1[n] = fmaxf(m1[n], om1);
            i1[n] = g ? oi : i1[n];
        }
    }
    float* sm1 = (float*)(smem + LDSM);
    float* sm2 = (float*)(smem + LDSM + 2048);
    int*   si1 = (int*)  (smem + LDSM + 4096);
    __syncthreads();
    if (q == 0) {
        #pragma unroll
        for (int n = 0; n < 4; ++n) {
            const int row = wn * 64 + n * 16 + lr;
            sm1[wm * 128 + row] = m1[n];
            sm2[wm * 128 + row] = m2[n];
            si1[wm * 128 + row] = i1[n];
        }
    }
    __syncthreads();
    if (tid < 128) {
        float a1 = sm1[tid], a2 = sm2[tid]; int ai = si1[tid];
        #pragma unroll
        for (int wq = 1; wq < 4; ++wq) {
            const float b1 = sm1[wq * 128 + tid], b2 = sm2[wq * 128 + tid];
            const int bi = si1[wq * 128 + tid];
            const bool g = b1 > a1;
            a2 = fmaxf(fminf(a1, b1), fmaxf(a2, b2));
            a1 = fmaxf(a1, b1);
            ai = g ? bi : ai;
        }
        const int n = n0 + tid;
        ids[n] = ai;
        atomicAdd(&counts[ai], 1);
        if (a1 - a2 < 2.5e-3f) {
            int p = atomicAdd(flag_cnt, 1);
            flag_list[p] = n;
        }
    }
}

// batched numpy-fp32-path rescore: 16 rows/group x 8 k-slices per block.
#define RG 16
__global__ __launch_bounds__(256) void k_rescore(
    const float* __restrict__ x, const float* __restrict__ embedT,
    const float* __restrict__ e2np, const int* __restrict__ flag_cnt,
    const int* __restrict__ flag_list, float* __restrict__ pbd, int* __restrict__ pbi)
{
    __shared__ float rowl[RG][256];
    __shared__ float sq[RG][256];
    __shared__ float x2s[RG];
    __shared__ float bdA[256];
    __shared__ int   biA[256];
    const int tid = threadIdx.x;
    int cnt = *flag_cnt; if (cnt > 2048) cnt = 2048;
    const int ngroups = (cnt + RG - 1) / RG;
    const int kt = blockIdx.x & 7;
    for (int g = blockIdx.x >> 3; g < ngroups; g += 64) {
        #pragma unroll
        for (int i = 0; i < RG; ++i) {
            int f = g * RG + i;
            float v = 0.f;
            if (f < cnt) {
                int n = flag_list[f];
                int b = n >> 10, wq = (n >> 5) & 31, hq = n & 31;
                v = x[((size_t)(b * 256 + tid)) * 1024 + hq * 32 + wq];
            }
            rowl[i][tid] = v;
            sq[i][tid] = v * v;       // product rounds at LDS store
        }
        __syncthreads();
        if (tid < RG) x2s[tid] = np_pw128(sq[tid]) + np_pw128(sq[tid] + 128);
        __syncthreads();

        float acc[RG][4];
        #pragma unroll
        for (int r = 0; r < RG; ++r)
            #pragma unroll
            for (int e = 0; e < 4; ++e) acc[r][e] = 0.f;
        for (int c = 0; c < 256; ++c) {
            const f32x4 bv = *(const f32x4*)&embedT[(size_t)c * KD + kt * 1024 + tid * 4];
            #pragma unroll
            for (int r = 0; r < RG; ++r) {
                const float av = rowl[r][c];
                acc[r][0] = fmaf(av, bv[0], acc[r][0]);
                acc[r][1] = fmaf(av, bv[1], acc[r][1]);
                acc[r][2] = fmaf(av, bv[2], acc[r][2]);
                acc[r][3] = fmaf(av, bv[3], acc[r][3]);
            }
        }
        #pragma unroll
        for (int r = 0; r < RG; ++r) {
            float bd = 3.4e38f; int bi = 0x7fffffff;
            #pragma unroll
            for (int e = 0; e < 4; ++e) {
                const int k = kt * 1024 + tid * 4 + e;
                const float d2 = (x2s[r] - 2.0f * acc[r][e]) + e2np[k];
                if (d2 < bd || (d2 == bd && k < bi)) { bd = d2; bi = k; }
            }
            bdA[tid] = bd; biA[tid] = bi;
            __syncthreads();
            for (int off = 128; off > 0; off >>= 1) {
                if (tid < off) {
                    float od = bdA[tid + off]; int oi = biA[tid + off];
                    if (od < bdA[tid] || (od == bdA[tid] && oi < biA[tid])) {
                        bdA[tid] = od; biA[tid] = oi;
                    }
                }
                __syncthreads();
            }
            if (tid == 0) {
                int f = g * RG + r;
                if (f < cnt) { pbd[f * 8 + kt] = bdA[0]; pbi[f * 8 + kt] = biA[0]; }
            }
            __syncthreads();
        }
    }
}

// merge kt-slices; adjust ids + counts for changed rows
__global__ void k_flagmerge(const int* __restrict__ flag_cnt, const int* __restrict__ flag_list,
                            const float* __restrict__ pbd, const int* __restrict__ pbi,
                            int* __restrict__ ids, int* __restrict__ counts) {
    int cnt = *flag_cnt; if (cnt > 2048) cnt = 2048;
    int f = blockIdx.x * 256 + threadIdx.x;
    if (f >= cnt) return;
    float bd = pbd[f * 8]; int bi = pbi[f * 8];
    #pragma unroll
    for (int kt = 1; kt < 8; ++kt) {
        float d = pbd[f * 8 + kt]; int i = pbi[f * 8 + kt];
        if (d < bd || (d == bd && i < bi)) { bd = d; bi = i; }
    }
    const int n = flag_list[f];
    const int old = ids[n];
    if (bi != old) {
        ids[n] = bi;
        atomicAdd(&counts[old], -1);
        atomicAdd(&counts[bi], 1);
    }
}

// st_out (= vqs) + loss, fully coalesced via LDS transpose.
// block = (b,h): 32 pixels (w) x 256 channels.
__global__ __launch_bounds__(256) void k_output(
    const float* __restrict__ x, const float* __restrict__ embed,
    const int* __restrict__ ids, float* __restrict__ st,
    float* __restrict__ loss_ws)
{
    const int b = blockIdx.x >> 5, h = blockIdx.x & 31;
    const int tid = threadIdx.x;
    __shared__ int sid[32];
    __shared__ float vq[256 * 33];
    if (tid < 32) sid[tid] = ids[b * 1024 + tid * 32 + h];
    __syncthreads();
    // phase 1: coalesced embed-row reads -> vq[c][w]
    #pragma unroll 4
    for (int w = 0; w < 32; ++w) {
        vq[tid * 33 + w] = embed[(size_t)sid[w] * CD + tid];
    }
    __syncthreads();
    // phase 2: coalesced x-read / st-write; fuse loss
    float lsum = 0.f;
    const size_t base0 = (((size_t)b * 256) * 32 + h) * 32;
    #pragma unroll 8
    for (int it = 0; it < 32; ++it) {
        const int c = it * 8 + (tid >> 5);
        const int w = tid & 31;
        const size_t a = base0 + (size_t)c * 1024 + w;
        const float v = vq[c * 33 + w];
        const float xv = x[a];
        st[a] = v;
        const float d = v - xv;
        lsum = fmaf(d, d, lsum);
    }
    #pragma unroll
    for (int off = 1; off < 64; off <<= 1) lsum += __shfl_xor(lsum, off);
    if ((tid & 63) == 0) atomicAdd(loss_ws, lsum);
}

__global__ void k_ids(const int* __restrict__ ids, float* __restrict__ ids_out) {
    int e = blockIdx.x * 256 + threadIdx.x;
    int b = e >> 10, h = (e >> 5) & 31, w = e & 31;
    ids_out[e] = (float)ids[b * 1024 + w * 32 + h];
}

__global__ void k_scan(const int* __restrict__ counts, int* __restrict__ offs,
                       float* __restrict__ track_num) {
    __shared__ int ps[257];
    const int tid = threadIdx.x;
    int loc[32]; int s = 0;
    const int base = tid * 32;
    #pragma unroll
    for (int j = 0; j < 32; ++j) { loc[j] = s; s += counts[base + j]; }
    ps[tid + 1] = s;
    if (tid == 0) ps[0] = 0;
    __syncthreads();
    if (tid == 0) for (int i = 1; i <= 256; ++i) ps[i] += ps[i - 1];
    __syncthreads();
    const int pre = ps[tid];
    #pragma unroll
    for (int j = 0; j < 32; ++j) {
        offs[base + j] = pre + loc[j];
        track_num[base + j] = (float)counts[base + j];
    }
}

__global__ void k_fill(const int* __restrict__ ids, const int* __restrict__ offs,
                       int* __restrict__ cursor, int* __restrict__ bucket) {
    int n = blockIdx.x * 256 + threadIdx.x;
    int id = ids[n];
    int p = atomicAdd(&cursor[id], 1);
    bucket[offs[id] + p] = n;
}

// track_enc[k][c] = sum over bucket rows of (xh + xl)  (no atomics)
__global__ void k_gather(const _Float16* __restrict__ xh, const _Float16* __restrict__ xl,
                         const int* __restrict__ offs, const int* __restrict__ counts,
                         const int* __restrict__ bucket, float* __restrict__ enc) {
    const int k = blockIdx.x, c = threadIdx.x;
    const int o = offs[k], cnt = counts[k];
    float s = 0.f;
    for (int i = 0; i < cnt; ++i) {
        int n = bucket[o + i];
        s += (float)xh[(size_t)n * CD + c] + (float)xl[(size_t)n * CD + c];
    }
    enc[(size_t)k * CD + c] = s;
}

__global__ void k_final(const float* __restrict__ track_num, const float* __restrict__ track_enc,
                        float* __restrict__ new_embed, const float* __restrict__ loss_ws,
                        float* __restrict__ loss_out)
{
    const size_t e = (size_t)blockIdx.x * 256 + threadIdx.x;
    const int k = (int)(e >> 8);
    const float factor = 1.0f + (1e-5f * 8192.0f) / 32768.0f;
    new_embed[e] = track_enc[e] * factor / (track_num[k] + 1e-5f);
    if (e == 0) loss_out[0] = loss_ws[0] * (1.0f / 8388608.0f);
}

extern "C" void kernel_launch(void* const* d_in, const int* in_sizes, int n_in,
                              void* d_out, int out_size, void* d_ws, size_t ws_size,
                              hipStream_t stream)
{
    const float* x     = (const float*)d_in[0];
    const float* embed = (const float*)d_in[1];
    float* out = (float*)d_out;
    float* ws  = (float*)d_ws;

    _Float16* xh = (_Float16*)(ws + F_XH);
    _Float16* xl = (_Float16*)(ws + F_XL);
    _Float16* eh = (_Float16*)(ws + F_EH);
    float* embedT    = ws + F_EMBT;
    float* e2n       = ws + F_E2N;
    float* e2np      = ws + F_E2NP;
    int*   ids       = (int*)(ws + F_IDS);
    int*   flag_cnt  = (int*)(ws + F_FLAGCNT);
    float* loss_ws   = ws + F_LOSS;
    int*   flag_list = (int*)(ws + F_FLAGLST);
    int*   counts    = (int*)(ws + F_COUNTS);
    int*   cursor    = (int*)(ws + F_CURSOR);
    int*   offs      = (int*)(ws + F_OFFS);
    int*   bucket    = (int*)(ws + F_BUCKET);
    float* pbd       = ws + F_PBD;
    int*   pbi       = (int*)(ws + F_PBI);

    hipMemsetAsync(ws + F_FLAGCNT, 0, 2 * sizeof(float), stream);          // flag_cnt + loss
    hipMemsetAsync(ws + F_COUNTS, 0, 2 * 8192 * sizeof(float), stream);    // counts + cursor

    k_cvt_x    <<<512,  256, 0, stream>>>(x, xh, xl);
    k_prep_e   <<<2048, 256, 0, stream>>>(embed, eh, e2n);
    k_e2np     <<<256,  256, 0, stream>>>(embed, e2np);
    k_epose    <<<512,  256, 0, stream>>>(embed, embedT);
    k_mfma     <<<256,  512, 0, stream>>>(xh, eh, e2n, ids, flag_cnt, flag_list, counts);
    k_rescore  <<<512,  256, 0, stream>>>(x, embedT, e2np, flag_cnt, flag_list, pbd, pbi);
    k_flagmerge<<<8,    256, 0, stream>>>(flag_cnt, flag_list, pbd, pbi, ids, counts);
    k_output   <<<1024, 256, 0, stream>>>(x, embed, ids, out + OUT_ST, loss_ws);
    k_ids      <<<128,  256, 0, stream>>>(ids, out + OUT_IDS);
    k_scan     <<<1,    256, 0, stream>>>(counts, offs, out + OUT_NUM);
    k_fill     <<<128,  256, 0, stream>>>(ids, offs, cursor, bucket);
    k_gather   <<<8192, 256, 0, stream>>>(xh, xl, offs, counts, bucket, out + OUT_ENC);
    k_final    <<<8192, 256, 0, stream>>>(out + OUT_NUM, out + OUT_ENC, out + OUT_NEMB,
                                          loss_ws, out + OUT_LOSS);
}

// Round 7
// 372.875 us; speedup vs baseline: 13.0574x; 1.2364x over previous
//
#include <hip/hip_runtime.h>

#define NR 32768   // rows (b*w*h)
#define CD 256     // emb dim
#define KD 8192    // dict size

typedef __attribute__((ext_vector_type(8))) _Float16 f16x8;
typedef __attribute__((ext_vector_type(4))) _Float16 f16x4;
typedef __attribute__((ext_vector_type(4))) float f32x4;

// ---- workspace float offsets ----
#define F_XH      0ull          // f16[32768][256] hi  (16MB)
#define F_XL      4194304ull    // f16[32768][256] lo  (16MB)
#define F_EH      8388608ull    // f16[8192][256] hi   (4MB)
#define F_EMBT    9437184ull    // fp32 embedT[256][8192] (8MB, rescore)
#define F_E2N     11534336ull   // 8192  (-0.5*e2, fast path)
#define F_E2NP    11542528ull   // 8192  (numpy-emulated e2)
#define F_IDS     11550720ull   // 32768 ints
#define F_FLAGCNT 11583488ull
#define F_LOSS    11583489ull
#define F_FLAGLST 11583490ull   // up to 32768 ints
#define F_COUNTS  11616258ull   // 8192 ints
#define F_CURSOR  11624450ull   // 8192 ints
#define F_OFFS    11632642ull   // 8192 ints
#define F_BUCKET  11640834ull   // 32768 ints
#define F_PBD     11673602ull   // 2048*8 floats
#define F_PBI     11689986ull   // 2048*8 ints

// ---- output float offsets ----
#define OUT_ST   0ull
#define OUT_LOSS 8388608ull
#define OUT_IDS  8388609ull
#define OUT_NEMB 8421377ull
#define OUT_NUM  10518529ull
#define OUT_ENC  10526721ull

// numpy pairwise_sum for a 128-block: 8 accumulators, fixed combine tree.
__device__ __forceinline__ float np_pw128(const float* p) {
    float r0 = p[0], r1 = p[1], r2 = p[2], r3 = p[3];
    float r4 = p[4], r5 = p[5], r6 = p[6], r7 = p[7];
    for (int i = 8; i < 128; i += 8) {
        r0 += p[i + 0]; r1 += p[i + 1]; r2 += p[i + 2]; r3 += p[i + 3];
        r4 += p[i + 4]; r5 += p[i + 5]; r6 += p[i + 6]; r7 += p[i + 7];
    }
    return ((r0 + r1) + (r2 + r3)) + ((r4 + r5) + (r6 + r7));
}

// x (b,c,h,w) -> xh/xl[n][c] f16 split, n = b*1024 + w*32 + h
__global__ void k_cvt_x(const float* __restrict__ x,
                        _Float16* __restrict__ xh, _Float16* __restrict__ xl) {
    __shared__ float t[32 * 529];   // [c32][h16*33 + w]
    const int bx = blockIdx.x;
    const int b = bx >> 4, cg = (bx >> 1) & 7, h0 = (bx & 1) * 16;
    const int tid = threadIdx.x;
    const float* src = x + ((size_t)(b * 256 + cg * 32)) * 1024 + h0 * 32;
    for (int i = 0; i < 64; ++i) {
        int e = i * 256 + tid;
        int c = e >> 9, rem = e & 511;
        int hh = rem >> 5, w = rem & 31;
        t[c * 529 + hh * 33 + w] = src[(size_t)c * 1024 + hh * 32 + w];
    }
    __syncthreads();
    const int ni = tid >> 5, c = tid & 31;
    for (int i = 0; i < 64; ++i) {
        int ns = i * 8 + ni;             // 0..511 = w*16 + hh
        int w = ns >> 4, hh = ns & 15;
        float v = t[c * 529 + hh * 33 + w];
        _Float16 hi = (_Float16)v;
        _Float16 lo = (_Float16)(v - (float)hi);
        size_t o = ((size_t)(b * 1024 + w * 32 + h0 + hh)) * 256 + cg * 32 + c;
        xh[o] = hi; xl[o] = lo;
    }
}

// embed -> eh f16 (hi only) + e2n = -0.5*|e|^2
__global__ void k_prep_e(const float* __restrict__ embed,
                         _Float16* __restrict__ eh, float* __restrict__ e2n) {
    int wave = threadIdx.x >> 6, lane = threadIdx.x & 63;
    int k = blockIdx.x * 4 + wave;
    float4 v = *(const float4*)(embed + (size_t)k * CD + lane * 4);
    f16x4 h;
    h[0] = (_Float16)v.x; h[1] = (_Float16)v.y;
    h[2] = (_Float16)v.z; h[3] = (_Float16)v.w;
    *(f16x4*)&eh[(size_t)k * CD + lane * 4] = h;
    float s = v.x * v.x + v.y * v.y + v.z * v.z + v.w * v.w;
    #pragma unroll
    for (int off = 1; off < 64; off <<= 1) s += __shfl_xor(s, off);
    if (lane == 0) e2n[k] = -0.5f * s;
}

// numpy-emulated e2, wave-parallel: 8 lanes per k, exact pairwise tree.
__global__ void k_e2np(const float* __restrict__ embed, float* __restrict__ e2np) {
    const int lane = threadIdx.x & 63;
    const int wv = threadIdx.x >> 6;
    const int k = blockIdx.x * 32 + wv * 8 + (lane >> 3);
    const int j = lane & 7;
    float hsum[2];
    #pragma unroll
    for (int half = 0; half < 2; ++half) {
        float r = 0.f;
        for (int i = 0; i < 16; ++i) {
            float v = embed[(size_t)k * CD + half * 128 + j + i * 8];
            float sq = v * v;
            asm volatile("" : "+v"(sq));   // round v*v to fp32 (block contraction)
            r += sq;
        }
        float s = r + __shfl_xor(r, 1);
        s = s + __shfl_xor(s, 2);
        s = s + __shfl_xor(s, 4);
        hsum[half] = s;
    }
    if (j == 0) e2np[k] = hsum[0] + hsum[1];
}

// embed (k,c) -> embedT[c][k] fp32 (rescore only)
__global__ void k_epose(const float* __restrict__ embed, float* __restrict__ embedT) {
    int kt = blockIdx.x >> 2, ct = blockIdx.x & 3;
    __shared__ float t[64][65];
    int tid = threadIdx.x;
    #pragma unroll
    for (int i = 0; i < 16; ++i) {
        int e = tid + i * 256; int r = e >> 6, c = e & 63;
        t[r][c] = embed[(size_t)(kt * 64 + r) * CD + ct * 64 + c];
    }
    __syncthreads();
    #pragma unroll
    for (int i = 0; i < 16; ++i) {
        int e = tid + i * 256; int c = e >> 6, r = e & 63;
        embedT[(size_t)(ct * 64 + c) * KD + kt * 64 + r] = t[r][c];
    }
}

// ============================================================================
// Operand-swapped MFMA argmin with counted-vmcnt pipeline (T3+T4).
// B (xh, 128 rows) resident 64KB; A (eh) quad-buffered 4x16KB chunks
// (256 codes x 32 c), 3-deep prefetch, vmcnt(4) + raw s_barrier per step.
// MFMA C-init carries the -0.5*e2 bias (no acc re-init movs).
// ============================================================================
#define LDSB 0
#define LDSA 65536
#define LDSM 131072
__global__ __launch_bounds__(512, 1) void k_mfma(
    const _Float16* __restrict__ xh, const _Float16* __restrict__ eh,
    const float* __restrict__ e2n, int* __restrict__ ids,
    int* __restrict__ flag_cnt, int* __restrict__ flag_list,
    int* __restrict__ counts)
{
    __shared__ char smem[131072 + 6144];   // B 64KB | A 4x16KB | merge/dummy 6KB
    const int tid = threadIdx.x;
    const int w = tid >> 6, l = tid & 63;
    const int wm = w & 3, wn = w >> 2;        // 4 code-waves x 2 row-waves
    const int lr = l & 15, q = l >> 4;
    const int n0 = blockIdx.x * 128;

    // ---- stage B (xh rows) resident, swizzled slot' = slot ^ (row&15) ----
    #pragma unroll
    for (int i = 0; i < 8; ++i) {
        const int row = i * 16 + (tid >> 5);
        const int slot = tid & 31;
        const _Float16* src = xh + (size_t)(n0 + row) * 256 + ((slot ^ (row & 15)) * 8);
        __builtin_amdgcn_global_load_lds(
            (const __attribute__((address_space(1))) unsigned int*)src,
            (__attribute__((address_space(3))) unsigned int*)(smem + LDSB + row * 512 + slot * 16),
            16, 0, 0);
    }

    // ---- A stage: step s covers codes [(s>>3)*256, +256) x c [(s&7)*32, +32).
    // 2 x global_load_lds(16B) per thread; dummy loads keep vmcnt count exact.
    auto STAGE_A = [&](int s, int bufc) {
        if (s < 256) {
            const int bufo = LDSA + bufc * 16384;
            #pragma unroll
            for (int i = 0; i < 2; ++i) {
                const int code = i * 128 + (tid >> 2);
                const int slot = tid & 3;
                const _Float16* src = eh + (size_t)((s >> 3) * 256 + code) * 256
                                         + (s & 7) * 32 + ((slot ^ ((code >> 1) & 3)) * 8);
                __builtin_amdgcn_global_load_lds(
                    (const __attribute__((address_space(1))) unsigned int*)src,
                    (__attribute__((address_space(3))) unsigned int*)
                        (smem + bufo + code * 64 + slot * 16),
                    16, 0, 0);
            }
        } else {
            #pragma unroll
            for (int i = 0; i < 2; ++i) {
                __builtin_amdgcn_global_load_lds(
                    (const __attribute__((address_space(1))) unsigned int*)(eh + tid * 8),
                    (__attribute__((address_space(3))) unsigned int*)
                        (smem + LDSM + i * 1024 + (tid & 63) * 16),
                    16, 0, 0);
            }
        }
    };

    // ---- prologue: e2 bias for window 0, stage steps 0..2, wait step0 ----
    f32x4 e2c[4];
    #pragma unroll
    for (int m = 0; m < 4; ++m)
        e2c[m] = *(const f32x4*)(e2n + wm * 64 + m * 16 + q * 4);
    STAGE_A(0, 0); STAGE_A(1, 1); STAGE_A(2, 2);
    __builtin_amdgcn_sched_barrier(0);
    asm volatile("s_waitcnt vmcnt(4)" ::: "memory");
    __builtin_amdgcn_s_barrier();
    __builtin_amdgcn_sched_barrier(0);

    f32x4 acc[4][4];
    float m1[4], m2[4]; int i1[4];
    #pragma unroll
    for (int n = 0; n < 4; ++n) { m1[n] = -3.4e38f; m2[n] = -3.4e38f; i1[n] = 0; }

    // precomputed LDS offsets
    int faoff[4];
    #pragma unroll
    for (int m = 0; m < 4; ++m) {
        const int code = wm * 64 + m * 16 + lr;
        faoff[m] = code * 64 + ((q ^ ((code >> 1) & 3)) * 16);
    }
    int fboff[4], rx[4];
    #pragma unroll
    for (int n = 0; n < 4; ++n) {
        const int row = wn * 64 + n * 16 + lr;
        fboff[n] = LDSB + row * 512;
        rx[n] = row & 15;
    }

    #pragma unroll 1
    for (int cg = 0; cg < 32; ++cg) {
        #pragma unroll
        for (int cc = 0; cc < 8; ++cc) {
            const int s = cg * 8 + cc;
            if (cc == 6 && cg < 31) {   // prefetch next window's e2 bias (VMEM, safe w.r.t. vmcnt(4))
                #pragma unroll
                for (int m = 0; m < 4; ++m)
                    e2c[m] = *(const f32x4*)(e2n + (cg + 1) * 256 + wm * 64 + m * 16 + q * 4);
            }
            STAGE_A(s + 3, (cc + 3) & 3);
            const int bufo = LDSA + (cc & 3) * 16384;
            f16x8 fa[4], fb[4];
            #pragma unroll
            for (int m = 0; m < 4; ++m)
                fa[m] = *(const f16x8*)(smem + bufo + faoff[m]);
            #pragma unroll
            for (int n = 0; n < 4; ++n)
                fb[n] = *(const f16x8*)(smem + fboff[n] + (((cc * 4 + q) ^ rx[n]) * 16));
            if (cc == 0) {
                #pragma unroll
                for (int m = 0; m < 4; ++m)
                    #pragma unroll
                    for (int n = 0; n < 4; ++n)
                        acc[m][n] = __builtin_amdgcn_mfma_f32_16x16x32_f16(fa[m], fb[n], e2c[m], 0, 0, 0);
            } else {
                #pragma unroll
                for (int m = 0; m < 4; ++m)
                    #pragma unroll
                    for (int n = 0; n < 4; ++n)
                        acc[m][n] = __builtin_amdgcn_mfma_f32_16x16x32_f16(fa[m], fb[n], acc[m][n], 0, 0, 0);
            }
            if (cc == 7) {   // fold window into per-lane top-2
                const int kb = cg * 256 + wm * 64 + q * 4;
                #pragma unroll
                for (int n = 0; n < 4; ++n)
                    #pragma unroll
                    for (int m = 0; m < 4; ++m)
                        #pragma unroll
                        for (int r = 0; r < 4; ++r) {
                            const float v = acc[m][n][r];
                            const bool g = v > m1[n];
                            m2[n] = fmaxf(m2[n], fminf(v, m1[n]));
                            m1[n] = fmaxf(m1[n], v);
                            i1[n] = g ? (kb + m * 16 + r) : i1[n];
                        }
            }
            __builtin_amdgcn_sched_barrier(0);
            asm volatile("s_waitcnt vmcnt(4)" ::: "memory");
            __builtin_amdgcn_s_barrier();
            __builtin_amdgcn_sched_barrier(0);
        }
    }

    // ---- cross-lane merge: lanes l, l+16, l+32, l+48 hold same row, diff codes
    #pragma unroll
    for (int off = 16; off < 64; off <<= 1) {
        #pragma unroll
        for (int n = 0; n < 4; ++n) {
            const float om1 = __shfl_xor(m1[n], off);
            const float om2 = __shfl_xor(m2[n], off);
            const int   oi  = __shfl_xor(i1[n], off);
            const bool g = om1 > m1[n];
            m2[n] = fmaxf(fminf(m1[n], om1), fmaxf(m2[n], om2));
            m1[n] = fmaxf(m1[n], om1);
            i1[n] = g ? oi : i1[n];
        }
    }
    // ---- cross-wave merge over wm (4 code-wave groups) via LDS ----
    float* sm1 = (float*)(smem + LDSM);
    float* sm2 = (float*)(smem + LDSM + 2048);
    int*   si1 = (int*)  (smem + LDSM + 4096);
    __syncthreads();    // full drain (incl. dummy loads into LDSM)
    if (q == 0) {
        #pragma unroll
        for (int n = 0; n < 4; ++n) {
            const int row = wn * 64 + n * 16 + lr;
            sm1[wm * 128 + row] = m1[n];
            sm2[wm * 128 + row] = m2[n];
            si1[wm * 128 + row] = i1[n];
        }
    }
    __syncthreads();
    if (tid < 128) {
        float a1 = sm1[tid], a2 = sm2[tid]; int ai = si1[tid];
        #pragma unroll
        for (int wq = 1; wq < 4; ++wq) {
            const float b1 = sm1[wq * 128 + tid], b2 = sm2[wq * 128 + tid];
            const int bi = si1[wq * 128 + tid];
            const bool g = b1 > a1;
            a2 = fmaxf(fminf(a1, b1), fmaxf(a2, b2));
            a1 = fmaxf(a1, b1);
            ai = g ? bi : ai;
        }
        const int n = n0 + tid;
        ids[n] = ai;
        atomicAdd(&counts[ai], 1);
        if (a1 - a2 < 2.5e-3f) {
            int p = atomicAdd(flag_cnt, 1);
            flag_list[p] = n;
        }
    }
}

// batched numpy-fp32-path rescore: 16 rows/group x 8 k-slices per block.
#define RG 16
__global__ __launch_bounds__(256) void k_rescore(
    const float* __restrict__ x, const float* __restrict__ embedT,
    const float* __restrict__ e2np, const int* __restrict__ flag_cnt,
    const int* __restrict__ flag_list, float* __restrict__ pbd, int* __restrict__ pbi)
{
    __shared__ float rowl[RG][256];
    __shared__ float sq[RG][256];
    __shared__ float x2s[RG];
    __shared__ float bdA[256];
    __shared__ int   biA[256];
    const int tid = threadIdx.x;
    int cnt = *flag_cnt; if (cnt > 2048) cnt = 2048;
    const int ngroups = (cnt + RG - 1) / RG;
    const int kt = blockIdx.x & 7;
    for (int g = blockIdx.x >> 3; g < ngroups; g += 64) {
        #pragma unroll
        for (int i = 0; i < RG; ++i) {
            int f = g * RG + i;
            float v = 0.f;
            if (f < cnt) {
                int n = flag_list[f];
                int b = n >> 10, wq = (n >> 5) & 31, hq = n & 31;
                v = x[((size_t)(b * 256 + tid)) * 1024 + hq * 32 + wq];
            }
            rowl[i][tid] = v;
            sq[i][tid] = v * v;       // product rounds at LDS store
        }
        __syncthreads();
        if (tid < RG) x2s[tid] = np_pw128(sq[tid]) + np_pw128(sq[tid] + 128);
        __syncthreads();

        float acc[RG][4];
        #pragma unroll
        for (int r = 0; r < RG; ++r)
            #pragma unroll
            for (int e = 0; e < 4; ++e) acc[r][e] = 0.f;
        for (int c = 0; c < 256; ++c) {
            const f32x4 bv = *(const f32x4*)&embedT[(size_t)c * KD + kt * 1024 + tid * 4];
            #pragma unroll
            for (int r = 0; r < RG; ++r) {
                const float av = rowl[r][c];
                acc[r][0] = fmaf(av, bv[0], acc[r][0]);
                acc[r][1] = fmaf(av, bv[1], acc[r][1]);
                acc[r][2] = fmaf(av, bv[2], acc[r][2]);
                acc[r][3] = fmaf(av, bv[3], acc[r][3]);
            }
        }
        #pragma unroll
        for (int r = 0; r < RG; ++r) {
            float bd = 3.4e38f; int bi = 0x7fffffff;
            #pragma unroll
            for (int e = 0; e < 4; ++e) {
                const int k = kt * 1024 + tid * 4 + e;
                const float d2 = (x2s[r] - 2.0f * acc[r][e]) + e2np[k];
                if (d2 < bd || (d2 == bd && k < bi)) { bd = d2; bi = k; }
            }
            bdA[tid] = bd; biA[tid] = bi;
            __syncthreads();
            for (int off = 128; off > 0; off >>= 1) {
                if (tid < off) {
                    float od = bdA[tid + off]; int oi = biA[tid + off];
                    if (od < bdA[tid] || (od == bdA[tid] && oi < biA[tid])) {
                        bdA[tid] = od; biA[tid] = oi;
                    }
                }
                __syncthreads();
            }
            if (tid == 0) {
                int f = g * RG + r;
                if (f < cnt) { pbd[f * 8 + kt] = bdA[0]; pbi[f * 8 + kt] = biA[0]; }
            }
            __syncthreads();
        }
    }
}

// merge kt-slices; adjust ids + counts for changed rows
__global__ void k_flagmerge(const int* __restrict__ flag_cnt, const int* __restrict__ flag_list,
                            const float* __restrict__ pbd, const int* __restrict__ pbi,
                            int* __restrict__ ids, int* __restrict__ counts) {
    int cnt = *flag_cnt; if (cnt > 2048) cnt = 2048;
    int f = blockIdx.x * 256 + threadIdx.x;
    if (f >= cnt) return;
    float bd = pbd[f * 8]; int bi = pbi[f * 8];
    #pragma unroll
    for (int kt = 1; kt < 8; ++kt) {
        float d = pbd[f * 8 + kt]; int i = pbi[f * 8 + kt];
        if (d < bd || (d == bd && i < bi)) { bd = d; bi = i; }
    }
    const int n = flag_list[f];
    const int old = ids[n];
    if (bi != old) {
        ids[n] = bi;
        atomicAdd(&counts[old], -1);
        atomicAdd(&counts[bi], 1);
    }
}

// st_out (= vqs) + loss, fully coalesced via LDS transpose.
// block = (b,h): 32 pixels (w) x 256 channels.
__global__ __launch_bounds__(256) void k_output(
    const float* __restrict__ x, const float* __restrict__ embed,
    const int* __restrict__ ids, float* __restrict__ st,
    float* __restrict__ loss_ws)
{
    const int b = blockIdx.x >> 5, h = blockIdx.x & 31;
    const int tid = threadIdx.x;
    __shared__ int sid[32];
    __shared__ float vq[256 * 33];
    if (tid < 32) sid[tid] = ids[b * 1024 + tid * 32 + h];
    __syncthreads();
    // phase 1: coalesced embed-row reads -> vq[c][w]
    #pragma unroll 4
    for (int w = 0; w < 32; ++w) {
        vq[tid * 33 + w] = embed[(size_t)sid[w] * CD + tid];
    }
    __syncthreads();
    // phase 2: coalesced x-read / st-write; fuse loss
    float lsum = 0.f;
    const size_t base0 = (((size_t)b * 256) * 32 + h) * 32;
    #pragma unroll 8
    for (int it = 0; it < 32; ++it) {
        const int c = it * 8 + (tid >> 5);
        const int w = tid & 31;
        const size_t a = base0 + (size_t)c * 1024 + w;
        const float v = vq[c * 33 + w];
        const float xv = x[a];
        st[a] = v;
        const float d = v - xv;
        lsum = fmaf(d, d, lsum);
    }
    #pragma unroll
    for (int off = 1; off < 64; off <<= 1) lsum += __shfl_xor(lsum, off);
    if ((tid & 63) == 0) atomicAdd(loss_ws, lsum);
}

__global__ void k_ids(const int* __restrict__ ids, float* __restrict__ ids_out) {
    int e = blockIdx.x * 256 + threadIdx.x;
    int b = e >> 10, h = (e >> 5) & 31, w = e & 31;
    ids_out[e] = (float)ids[b * 1024 + w * 32 + h];
}

__global__ void k_scan(const int* __restrict__ counts, int* __restrict__ offs,
                       float* __restrict__ track_num) {
    __shared__ int ps[257];
    const int tid = threadIdx.x;
    int loc[32]; int s = 0;
    const int base = tid * 32;
    #pragma unroll
    for (int j = 0; j < 32; ++j) { loc[j] = s; s += counts[base + j]; }
    ps[tid + 1] = s;
    if (tid == 0) ps[0] = 0;
    __syncthreads();
    if (tid == 0) for (int i = 1; i <= 256; ++i) ps[i] += ps[i - 1];
    __syncthreads();
    const int pre = ps[tid];
    #pragma unroll
    for (int j = 0; j < 32; ++j) {
        offs[base + j] = pre + loc[j];
        track_num[base + j] = (float)counts[base + j];
    }
}

__global__ void k_fill(const int* __restrict__ ids, const int* __restrict__ offs,
                       int* __restrict__ cursor, int* __restrict__ bucket) {
    int n = blockIdx.x * 256 + threadIdx.x;
    int id = ids[n];
    int p = atomicAdd(&cursor[id], 1);
    bucket[offs[id] + p] = n;
}

// track_enc[k][c] = sum over bucket rows of (xh + xl)  (no atomics)
__global__ void k_gather(const _Float16* __restrict__ xh, const _Float16* __restrict__ xl,
                         const int* __restrict__ offs, const int* __restrict__ counts,
                         const int* __restrict__ bucket, float* __restrict__ enc) {
    const int k = blockIdx.x, c = threadIdx.x;
    const int o = offs[k], cnt = counts[k];
    float s = 0.f;
    for (int i = 0; i < cnt; ++i) {
        int n = bucket[o + i];
        s += (float)xh[(size_t)n * CD + c] + (float)xl[(size_t)n * CD + c];
    }
    enc[(size_t)k * CD + c] = s;
}

__global__ void k_final(const float* __restrict__ track_num, const float* __restrict__ track_enc,
                        float* __restrict__ new_embed, const float* __restrict__ loss_ws,
                        float* __restrict__ loss_out)
{
    const size_t e = (size_t)blockIdx.x * 256 + threadIdx.x;
    const int k = (int)(e >> 8);
    const float factor = 1.0f + (1e-5f * 8192.0f) / 32768.0f;
    new_embed[e] = track_enc[e] * factor / (track_num[k] + 1e-5f);
    if (e == 0) loss_out[0] = loss_ws[0] * (1.0f / 8388608.0f);
}

extern "C" void kernel_launch(void* const* d_in, const int* in_sizes, int n_in,
                              void* d_out, int out_size, void* d_ws, size_t ws_size,
                              hipStream_t stream)
{
    const float* x     = (const float*)d_in[0];
    const float* embed = (const float*)d_in[1];
    float* out = (float*)d_out;
    float* ws  = (float*)d_ws;

    _Float16* xh = (_Float16*)(ws + F_XH);
    _Float16* xl = (_Float16*)(ws + F_XL);
    _Float16* eh = (_Float16*)(ws + F_EH);
    float* embedT    = ws + F_EMBT;
    float* e2n       = ws + F_E2N;
    float* e2np      = ws + F_E2NP;
    int*   ids       = (int*)(ws + F_IDS);
    int*   flag_cnt  = (int*)(ws + F_FLAGCNT);
    float* loss_ws   = ws + F_LOSS;
    int*   flag_list = (int*)(ws + F_FLAGLST);
    int*   counts    = (int*)(ws + F_COUNTS);
    int*   cursor    = (int*)(ws + F_CURSOR);
    int*   offs      = (int*)(ws + F_OFFS);
    int*   bucket    = (int*)(ws + F_BUCKET);
    float* pbd       = ws + F_PBD;
    int*   pbi       = (int*)(ws + F_PBI);

    hipMemsetAsync(ws + F_FLAGCNT, 0, 2 * sizeof(float), stream);          // flag_cnt + loss
    hipMemsetAsync(ws + F_COUNTS, 0, 2 * 8192 * sizeof(float), stream);    // counts + cursor

    k_cvt_x    <<<512,  256, 0, stream>>>(x, xh, xl);
    k_prep_e   <<<2048, 256, 0, stream>>>(embed, eh, e2n);
    k_e2np     <<<256,  256, 0, stream>>>(embed, e2np);
    k_epose    <<<512,  256, 0, stream>>>(embed, embedT);
    k_mfma     <<<256,  512, 0, stream>>>(xh, eh, e2n, ids, flag_cnt, flag_list, counts);
    k_rescore  <<<512,  256, 0, stream>>>(x, embedT, e2np, flag_cnt, flag_list, pbd, pbi);
    k_flagmerge<<<8,    256, 0, stream>>>(flag_cnt, flag_list, pbd, pbi, ids, counts);
    k_output   <<<1024, 256, 0, stream>>>(x, embed, ids, out + OUT_ST, loss_ws);
    k_ids      <<<128,  256, 0, stream>>>(ids, out + OUT_IDS);
    k_scan     <<<1,    256, 0, stream>>>(counts, offs, out + OUT_NUM);
    k_fill     <<<128,  256, 0, stream>>>(ids, offs, cursor, bucket);
    k_gather   <<<8192, 256, 0, stream>>>(xh, xl, offs, counts, bucket, out + OUT_ENC);
    k_final    <<<8192, 256, 0, stream>>>(out + OUT_NUM, out + OUT_ENC, out + OUT_NEMB,
                                          loss_ws, out + OUT_LOSS);
}